// Round 4
// baseline (734.921 us; speedup 1.0000x reference)
//
#include <hip/hip_runtime.h>

// Problem constants
constexpr int GG    = 512;          // graphs
constexpr int NPG   = 128;          // nodes per graph
constexpr int FIN   = 64;
constexpr int DD    = 128;
constexpr int RR    = 4;
constexpr int NN    = GG * NPG;     // 65536 nodes
constexpr int EE    = 1572864;      // edges
constexpr int NRSEG = NN * RR;      // 262144 segments (key = r*NN + dst)

typedef __attribute__((ext_vector_type(8))) short bf16x8;
typedef __attribute__((ext_vector_type(4))) float f32x4;

// ---------------- sort pipeline ----------------

__global__ __launch_bounds__(256) void k_hist(const int* __restrict__ ei,
                                              const int* __restrict__ ea,
                                              int* __restrict__ hist) {
    int e = blockIdx.x * 256 + threadIdx.x;
    if (e < EE) {
        int dst = ei[EE + e];
        int a   = ea[e];
        atomicAdd(&hist[a * NN + dst], 1);
    }
}

__global__ __launch_bounds__(256) void k_inv(const int* __restrict__ hist,
                                             float* __restrict__ inv) {
    int i = blockIdx.x * 256 + threadIdx.x;   // grid covers NRSEG exactly
    int c = hist[i];
    inv[i] = 1.0f / (float)(c > 0 ? c : 1);
}

// 262144 = 256 blocks * 1024 elems (4 per thread)
__global__ __launch_bounds__(256) void k_scan1(const int* __restrict__ hist,
                                               int* __restrict__ offs,
                                               int* __restrict__ bsum) {
    __shared__ int ts[256];
    int base = blockIdx.x * 1024 + threadIdx.x * 4;
    int4 v = *(const int4*)(hist + base);
    int s = v.x + v.y + v.z + v.w;
    ts[threadIdx.x] = s;
    __syncthreads();
    for (int ofs = 1; ofs < 256; ofs <<= 1) {
        int t = (threadIdx.x >= ofs) ? ts[threadIdx.x - ofs] : 0;
        __syncthreads();
        ts[threadIdx.x] += t;
        __syncthreads();
    }
    int excl = ts[threadIdx.x] - s;
    offs[base + 0] = excl;
    offs[base + 1] = excl + v.x;
    offs[base + 2] = excl + v.x + v.y;
    offs[base + 3] = excl + v.x + v.y + v.z;
    if (threadIdx.x == 255) bsum[blockIdx.x] = ts[255];
}

__global__ __launch_bounds__(256) void k_scan2(int* __restrict__ bsum) {
    __shared__ int ts[256];
    int v = bsum[threadIdx.x];
    ts[threadIdx.x] = v;
    __syncthreads();
    for (int ofs = 1; ofs < 256; ofs <<= 1) {
        int t = (threadIdx.x >= ofs) ? ts[threadIdx.x - ofs] : 0;
        __syncthreads();
        ts[threadIdx.x] += t;
        __syncthreads();
    }
    bsum[threadIdx.x] = ts[threadIdx.x] - v;   // exclusive
}

__global__ __launch_bounds__(256) void k_scan3(int* __restrict__ offs,
                                               const int* __restrict__ bsum,
                                               int* __restrict__ cursor) {
    int i = blockIdx.x * 256 + threadIdx.x;    // grid covers NRSEG
    int v = offs[i] + bsum[i >> 10];
    offs[i] = v;
    cursor[i] = v;
}

__global__ __launch_bounds__(256) void k_scatter(const int* __restrict__ ei,
                                                 const int* __restrict__ ea,
                                                 int* __restrict__ cursor,
                                                 unsigned* __restrict__ sorted) {
    int e = blockIdx.x * 256 + threadIdx.x;
    if (e < EE) {
        int src = ei[e];
        int dst = ei[EE + e];
        int a   = ea[e];
        int pos = atomicAdd(&cursor[a * NN + dst], 1);
        sorted[pos] = (unsigned)src;
    }
}

// ---------------- weight prep: transpose + split to bf16 hi/lo ----------------
// wt layout: mat = l*5 + {0=root, 1..4=rel r}; wt[mat*16384 + n*128 + k]
// (B-fragment-ready: row n contiguous in k)

__device__ __forceinline__ unsigned bf16_rne(float x) {
    unsigned u = __float_as_uint(x);
    return (u + 0x7FFFu + ((u >> 16) & 1u)) >> 16;
}

__global__ __launch_bounds__(256) void k_prep(const float* __restrict__ W_root,
                                              const float* __restrict__ W_rel,
                                              unsigned short* __restrict__ wtH,
                                              unsigned short* __restrict__ wtL) {
    int idx = blockIdx.x * 256 + threadIdx.x;   // grid covers 10*16384
    int mat = idx >> 14;
    int rem = idx & 16383;
    int n = rem >> 7, k = rem & 127;
    int l = mat / 5, m5 = mat - l * 5;
    float v = (m5 == 0) ? W_root[l * 16384 + k * 128 + n]
                        : W_rel[((l * RR + (m5 - 1)) * 128 + k) * 128 + n];
    unsigned hi = bf16_rne(v);
    float fh = __uint_as_float(hi << 16);
    unsigned lo = __float_as_uint(v - fh) >> 16;   // truncation is fine for the residue
    wtH[idx] = (unsigned short)hi;
    wtL[idx] = (unsigned short)lo;
}

// ---------------- embedding: h0 = x @ W_emb + b_emb ----------------

__global__ __launch_bounds__(256, 2) void k_embed(const float* __restrict__ x,
                                                  const float* __restrict__ W,
                                                  const float* __restrict__ b,
                                                  float* __restrict__ h) {
    __shared__ float sA[16 * 64];
    __shared__ float sB[16 * 128];
    int tid = threadIdx.x;
    int tx = tid & 31, ty = tid >> 5;
    int row0 = blockIdx.x * 64;

    float4 bv = *(const float4*)&b[tx * 4];
    float acc[8][4];
#pragma unroll
    for (int i = 0; i < 8; ++i) { acc[i][0]=bv.x; acc[i][1]=bv.y; acc[i][2]=bv.z; acc[i][3]=bv.w; }

    for (int kb = 0; kb < 4; ++kb) {
        {   // stage A: 64 rows x 16 k
            int rr = tid >> 2, kq = tid & 3;
            float4 v = *(const float4*)&x[(row0 + rr) * FIN + kb * 16 + kq * 4];
            sA[(kq*4+0)*64 + rr] = v.x;
            sA[(kq*4+1)*64 + rr] = v.y;
            sA[(kq*4+2)*64 + rr] = v.z;
            sA[(kq*4+3)*64 + rr] = v.w;
        }
#pragma unroll
        for (int i = 0; i < 2; ++i) {   // stage B: 16x128
            int f = tid + i * 256;
            *(float4*)&sB[f * 4] = *(const float4*)&W[kb * 16 * 128 + f * 4];
        }
        __syncthreads();
#pragma unroll
        for (int kk = 0; kk < 16; ++kk) {
            float4 a0 = *(const float4*)&sA[kk * 64 + ty * 4];
            float4 a1 = *(const float4*)&sA[kk * 64 + 32 + ty * 4];
            float4 bq = *(const float4*)&sB[kk * 128 + tx * 4];
            float ar[8] = {a0.x,a0.y,a0.z,a0.w,a1.x,a1.y,a1.z,a1.w};
#pragma unroll
            for (int i = 0; i < 8; ++i) {
                acc[i][0] = fmaf(ar[i], bq.x, acc[i][0]);
                acc[i][1] = fmaf(ar[i], bq.y, acc[i][1]);
                acc[i][2] = fmaf(ar[i], bq.z, acc[i][2]);
                acc[i][3] = fmaf(ar[i], bq.w, acc[i][3]);
            }
        }
        __syncthreads();
    }
#pragma unroll
    for (int i = 0; i < 8; ++i) {
        int row = (i < 4) ? (ty * 4 + i) : (32 + ty * 4 + (i - 4));
        float4 o; o.x = acc[i][0]; o.y = acc[i][1]; o.z = acc[i][2]; o.w = acc[i][3];
        *(float4*)&h[(row0 + row) * DD + tx * 4] = o;
    }
}

// ---------------- fused RGCN layer (MFMA, barrier-free) ----------------
// h_out = relu( h_in @ Wroot + sum_r mean_r(h_in) @ Wrel_r + bias )
// 256 threads = 4 waves; wave owns a 16-node M-strip (gather + MFMA A-operand).
// All LDS is wave-private -> NO __syncthreads in this kernel.
// A fragments: split-bf16 hi/lo in LDS, XOR-swizzled so gather-flush b64
// writes are 2-way (free); MFMA reads are contiguous ds_read_b128.
// B fragments: read straight from prepped global wt (L2-resident, 1.3 MB).

__global__ __launch_bounds__(256, 4) void k_layer(const float* __restrict__ hin,
                                                  float* __restrict__ hout,
                                                  const unsigned short* __restrict__ wtH,
                                                  const unsigned short* __restrict__ wtL,
                                                  const float* __restrict__ bias,
                                                  const unsigned* __restrict__ sorted,
                                                  const int* __restrict__ offs,
                                                  const float* __restrict__ inv) {
    __shared__ __align__(16) unsigned short fH[4 * 2048];  // 16 KB: [wave][kstep][16Bline][8]
    __shared__ __align__(16) unsigned short fL[4 * 2048];  // 16 KB
    __shared__ int sIdx[4 * 512];                          // 8 KB   -> total 40960 B

    int tid  = threadIdx.x;
    int wave = tid >> 6, lane = tid & 63;
    int half = lane >> 5;            // which node of the gather pair
    int qx   = lane & 31;            // feature quad: cols qx*4 .. qx*4+3
    int mm   = lane & 15;            // MFMA m (A) / n (B) lane index
    int quad = lane >> 4;            // MFMA quad
    int row0 = blockIdx.x * 64;
    int wbU  = wave * 2048;          // wave frag base (ushort units)
    int wb   = wave * 512;           // wave sIdx base

    f32x4 acc[8];
#pragma unroll
    for (int i = 0; i < 8; ++i) acc[i] = (f32x4){0.f, 0.f, 0.f, 0.f};

    // convert float4 -> hi/lo bf16x4 and store into wave's A-fragment region
    auto writeFrag = [&](int m, float4 v) {
        unsigned h0 = bf16_rne(v.x), h1 = bf16_rne(v.y);
        unsigned h2 = bf16_rne(v.z), h3 = bf16_rne(v.w);
        float r0 = v.x - __uint_as_float(h0 << 16);
        float r1 = v.y - __uint_as_float(h1 << 16);
        float r2 = v.z - __uint_as_float(h2 << 16);
        float r3 = v.w - __uint_as_float(h3 << 16);
        unsigned l0 = __float_as_uint(r0) >> 16, l1 = __float_as_uint(r1) >> 16;
        unsigned l2 = __float_as_uint(r2) >> 16, l3 = __float_as_uint(r3) >> 16;
        int kstep = qx >> 3, qd = (qx >> 1) & 3, par = qx & 1;
        int idx = ((kstep << 6) + (qd << 4) + (m ^ (qd | (kstep << 2)))) * 8 + par * 4;
        *(uint2*)&fH[wbU + idx] = make_uint2(h0 | (h1 << 16), h2 | (h3 << 16));
        *(uint2*)&fL[wbU + idx] = make_uint2(l0 | (l1 << 16), l2 | (l3 << 16));
    };

    // MFMA over current A-tile with weight matrix `mat` (split-bf16, 3 products)
    auto do_mat = [&](const unsigned short* __restrict__ BH,
                      const unsigned short* __restrict__ BL) {
        bf16x8 AH[4], AL[4];
#pragma unroll
        for (int ks = 0; ks < 4; ++ks) {
            int off16 = ks * 64 + quad * 16 + (mm ^ (quad | (ks << 2)));
            AH[ks] = *(const bf16x8*)&fH[wbU + off16 * 8];
            AL[ks] = *(const bf16x8*)&fL[wbU + off16 * 8];
        }
#pragma unroll
        for (int nt = 0; nt < 8; ++nt) {
            const unsigned short* bh = BH + (nt * 16 + mm) * 128 + quad * 8;
            const unsigned short* bl = BL + (nt * 16 + mm) * 128 + quad * 8;
            bf16x8 BHf[4], BLf[4];
#pragma unroll
            for (int ks = 0; ks < 4; ++ks) {
                BHf[ks] = *(const bf16x8*)&bh[ks * 32];
                BLf[ks] = *(const bf16x8*)&bl[ks * 32];
            }
            f32x4 a = acc[nt];
#pragma unroll
            for (int ks = 0; ks < 4; ++ks) {
                a = __builtin_amdgcn_mfma_f32_16x16x32_bf16(AH[ks], BHf[ks], a, 0, 0, 0);
                a = __builtin_amdgcn_mfma_f32_16x16x32_bf16(AL[ks], BHf[ks], a, 0, 0, 0);
                a = __builtin_amdgcn_mfma_f32_16x16x32_bf16(AH[ks], BLf[ks], a, 0, 0, 0);
            }
            acc[nt] = a;
        }
    };

    // ---- Part 1: root term. Stage hin strip -> frags, MFMA. ----
#pragma unroll
    for (int t2 = 0; t2 < 8; ++t2) {
        int m = t2 * 2 + half;
        float4 v = *(const float4*)&hin[(row0 + wave * 16 + m) * DD + qx * 4];
        writeFrag(m, v);
    }
    do_mat(wtH, wtL);

    // ---- Part 2: per-relation mean-aggregate -> frags, MFMA ----
    for (int g = 0; g < RR; ++g) {
        int bidx0 = g * NN + row0 + wave * 16;
        int w0 = offs[bidx0];
        int i16 = bidx0 + 16;
        int w1 = (i16 < NRSEG) ? offs[i16] : EE;
        int wcnt = w1 - w0;

        if (wcnt <= 512) {
            // prestage this wave's sorted-index range (coalesced), wave-private
            for (int i = lane; i < wcnt; i += 64) sIdx[wb + i] = (int)sorted[w0 + i];

            for (int t2 = 0; t2 < 8; ++t2) {     // 2 nodes in flight (half-waves)
                int m = t2 * 2 + half;
                int b = g * NN + row0 + wave * 16 + m;
                int r0 = offs[b];
                int r1 = (b + 1 < NRSEG) ? offs[b + 1] : EE;
                int o  = r0 - w0;
                int cnt = r1 - r0;
                float ax = 0.f, ay = 0.f, az = 0.f, aw = 0.f;
                int j = 0;
                for (; j + 8 <= cnt; j += 8) {
                    int i0 = sIdx[wb+o+j+0], i1 = sIdx[wb+o+j+1];
                    int i2 = sIdx[wb+o+j+2], i3 = sIdx[wb+o+j+3];
                    int i4 = sIdx[wb+o+j+4], i5 = sIdx[wb+o+j+5];
                    int i6 = sIdx[wb+o+j+6], i7 = sIdx[wb+o+j+7];
                    float4 v0 = *(const float4*)&hin[i0 * DD + qx * 4];
                    float4 v1 = *(const float4*)&hin[i1 * DD + qx * 4];
                    float4 v2 = *(const float4*)&hin[i2 * DD + qx * 4];
                    float4 v3 = *(const float4*)&hin[i3 * DD + qx * 4];
                    float4 v4 = *(const float4*)&hin[i4 * DD + qx * 4];
                    float4 v5 = *(const float4*)&hin[i5 * DD + qx * 4];
                    float4 v6 = *(const float4*)&hin[i6 * DD + qx * 4];
                    float4 v7 = *(const float4*)&hin[i7 * DD + qx * 4];
                    ax += (v0.x + v1.x) + (v2.x + v3.x) + (v4.x + v5.x) + (v6.x + v7.x);
                    ay += (v0.y + v1.y) + (v2.y + v3.y) + (v4.y + v5.y) + (v6.y + v7.y);
                    az += (v0.z + v1.z) + (v2.z + v3.z) + (v4.z + v5.z) + (v6.z + v7.z);
                    aw += (v0.w + v1.w) + (v2.w + v3.w) + (v4.w + v5.w) + (v6.w + v7.w);
                }
                for (; j + 4 <= cnt; j += 4) {
                    int i0 = sIdx[wb+o+j+0], i1 = sIdx[wb+o+j+1];
                    int i2 = sIdx[wb+o+j+2], i3 = sIdx[wb+o+j+3];
                    float4 v0 = *(const float4*)&hin[i0 * DD + qx * 4];
                    float4 v1 = *(const float4*)&hin[i1 * DD + qx * 4];
                    float4 v2 = *(const float4*)&hin[i2 * DD + qx * 4];
                    float4 v3 = *(const float4*)&hin[i3 * DD + qx * 4];
                    ax += (v0.x + v1.x) + (v2.x + v3.x);
                    ay += (v0.y + v1.y) + (v2.y + v3.y);
                    az += (v0.z + v1.z) + (v2.z + v3.z);
                    aw += (v0.w + v1.w) + (v2.w + v3.w);
                }
                for (; j < cnt; ++j) {
                    int i0 = sIdx[wb+o+j];
                    float4 v = *(const float4*)&hin[i0 * DD + qx * 4];
                    ax += v.x; ay += v.y; az += v.z; aw += v.w;
                }
                float s = inv[b];
                writeFrag(m, make_float4(ax * s, ay * s, az * s, aw * s));
            }
        } else {
            // rare fallback (range > 512): read indices straight from global
            for (int t2 = 0; t2 < 8; ++t2) {
                int m = t2 * 2 + half;
                int b = g * NN + row0 + wave * 16 + m;
                int r0 = offs[b];
                int r1 = (b + 1 < NRSEG) ? offs[b + 1] : EE;
                float ax = 0.f, ay = 0.f, az = 0.f, aw = 0.f;
                int e = r0;
                for (; e + 4 <= r1; e += 4) {
                    int i0 = (int)sorted[e], i1 = (int)sorted[e+1];
                    int i2 = (int)sorted[e+2], i3 = (int)sorted[e+3];
                    float4 v0 = *(const float4*)&hin[i0 * DD + qx * 4];
                    float4 v1 = *(const float4*)&hin[i1 * DD + qx * 4];
                    float4 v2 = *(const float4*)&hin[i2 * DD + qx * 4];
                    float4 v3 = *(const float4*)&hin[i3 * DD + qx * 4];
                    ax += (v0.x + v1.x) + (v2.x + v3.x);
                    ay += (v0.y + v1.y) + (v2.y + v3.y);
                    az += (v0.z + v1.z) + (v2.z + v3.z);
                    aw += (v0.w + v1.w) + (v2.w + v3.w);
                }
                for (; e < r1; ++e) {
                    int i0 = (int)sorted[e];
                    float4 v = *(const float4*)&hin[i0 * DD + qx * 4];
                    ax += v.x; ay += v.y; az += v.z; aw += v.w;
                }
                float s = inv[b];
                writeFrag(m, make_float4(ax * s, ay * s, az * s, aw * s));
            }
        }
        do_mat(wtH + (1 + g) * 16384, wtL + (1 + g) * 16384);
    }

    // ---- epilogue: bias + relu, C/D layout col=lane&15, row=quad*4+reg ----
    float bvs[8];
#pragma unroll
    for (int nt = 0; nt < 8; ++nt) bvs[nt] = bias[nt * 16 + mm];
#pragma unroll
    for (int nt = 0; nt < 8; ++nt) {
        int col = nt * 16 + mm;
#pragma unroll
        for (int r = 0; r < 4; ++r) {
            int node = row0 + wave * 16 + quad * 4 + r;
            hout[node * DD + col] = fmaxf(acc[nt][r] + bvs[nt], 0.f);
        }
    }
}

// ---------------- graph max-pool ----------------

__global__ __launch_bounds__(256) void k_maxpool(const float* __restrict__ h,
                                                 float* __restrict__ out) {
    __shared__ float4 red[256];
    int g = blockIdx.x;
    int tx = threadIdx.x & 31;     // col group (4 floats)
    int nn0 = threadIdx.x >> 5;    // 0..7
    int c4 = tx * 4;
    float4 m = make_float4(-1e30f, -1e30f, -1e30f, -1e30f);
    for (int nn = nn0; nn < NPG; nn += 8) {
        float4 v = *(const float4*)&h[(g * NPG + nn) * DD + c4];
        m.x = fmaxf(m.x, v.x); m.y = fmaxf(m.y, v.y);
        m.z = fmaxf(m.z, v.z); m.w = fmaxf(m.w, v.w);
    }
    red[threadIdx.x] = m;
    __syncthreads();
    if (nn0 == 0) {
#pragma unroll
        for (int i = 1; i < 8; ++i) {
            float4 v = red[i * 32 + tx];
            m.x = fmaxf(m.x, v.x); m.y = fmaxf(m.y, v.y);
            m.z = fmaxf(m.z, v.z); m.w = fmaxf(m.w, v.w);
        }
        *(float4*)&out[g * DD + c4] = m;
    }
}

// ---------------- launch ----------------

extern "C" void kernel_launch(void* const* d_in, const int* in_sizes, int n_in,
                              void* d_out, int out_size, void* d_ws, size_t ws_size,
                              hipStream_t stream) {
    const float* x      = (const float*)d_in[0];
    const int*   ei     = (const int*)  d_in[1];
    const int*   ea     = (const int*)  d_in[2];
    const float* W_emb  = (const float*)d_in[3];
    const float* b_emb  = (const float*)d_in[4];
    const float* W_root = (const float*)d_in[5];
    const float* W_rel  = (const float*)d_in[6];
    const float* bias   = (const float*)d_in[7];
    float* out = (float*)d_out;

    char* p = (char*)d_ws;
    float*    h0     = (float*)p;    p += (size_t)NN * DD * 4;      // 33.55 MB
    float*    h1     = (float*)p;    p += (size_t)NN * DD * 4;      // 33.55 MB
    int*      hist   = (int*)p;      p += (size_t)NRSEG * 4;        // 1 MB
    float*    inv    = (float*)p;    p += (size_t)NRSEG * 4;        // 1 MB
    int*      offs   = (int*)p;      p += (size_t)NRSEG * 4;        // 1 MB
    int*      cursor = (int*)p;      p += (size_t)NRSEG * 4;        // 1 MB
    int*      bsum   = (int*)p;      p += 1024;
    unsigned* sorted = (unsigned*)p; p += (size_t)EE * 4;           // 6.29 MB
    unsigned short* wtH = (unsigned short*)p; p += (size_t)10 * 16384 * 2;  // 0.33 MB
    unsigned short* wtL = (unsigned short*)p; p += (size_t)10 * 16384 * 2;  // 0.33 MB

    hipMemsetAsync(hist, 0, (size_t)NRSEG * 4, stream);

    k_prep   <<<640, 256, 0, stream>>>(W_root, W_rel, wtH, wtL);
    k_embed  <<<NN / 64, 256, 0, stream>>>(x, W_emb, b_emb, h0);
    k_hist   <<<EE / 256, 256, 0, stream>>>(ei, ea, hist);
    k_inv    <<<NRSEG / 256, 256, 0, stream>>>(hist, inv);
    k_scan1  <<<256, 256, 0, stream>>>(hist, offs, bsum);
    k_scan2  <<<1, 256, 0, stream>>>(bsum);
    k_scan3  <<<NRSEG / 256, 256, 0, stream>>>(offs, bsum, cursor);
    k_scatter<<<EE / 256, 256, 0, stream>>>(ei, ea, cursor, sorted);

    k_layer<<<NN / 64, 256, 0, stream>>>(h0, h1, wtH,         wtL,         bias,       sorted, offs, inv);
    k_layer<<<NN / 64, 256, 0, stream>>>(h1, h0, wtH + 81920, wtL + 81920, bias + 128, sorted, offs, inv);

    k_maxpool<<<GG, 256, 0, stream>>>(h0, out);
}

// Round 5
// 586.977 us; speedup vs baseline: 1.2520x; 1.2520x over previous
//
#include <hip/hip_runtime.h>

// Problem constants
constexpr int GG    = 512;          // graphs
constexpr int NPG   = 128;          // nodes per graph
constexpr int FIN   = 64;
constexpr int DD    = 128;
constexpr int RR    = 4;
constexpr int NN    = GG * NPG;     // 65536 nodes
constexpr int EE    = 1572864;      // edges
constexpr int NRSEG = NN * RR;      // 262144 segments (key = r*NN + dst)

typedef __attribute__((ext_vector_type(8))) short bf16x8;
typedef __attribute__((ext_vector_type(4))) float f32x4;
typedef unsigned short u16;
typedef unsigned int   u32;

__device__ __forceinline__ u32 bf16_rne(float x) {
    u32 u = __float_as_uint(x);
    return (u + 0x7FFFu + ((u >> 16) & 1u)) >> 16;
}

// async global->LDS DMA, 16 B per lane; LDS side must be uniform-base + lane*16
__device__ __forceinline__ void gl_lds16(const void* g, void* l) {
    __builtin_amdgcn_global_load_lds((const __attribute__((address_space(1))) u32*)g,
                                     (__attribute__((address_space(3))) u32*)l, 16, 0, 0);
}

// ---------------- sort pipeline ----------------

__global__ __launch_bounds__(256) void k_hist(const int* __restrict__ ei,
                                              const int* __restrict__ ea,
                                              int* __restrict__ hist) {
    int e = blockIdx.x * 256 + threadIdx.x;
    if (e < EE) {
        int dst = ei[EE + e];
        int a   = ea[e];
        atomicAdd(&hist[a * NN + dst], 1);
    }
}

// 262144 = 256 blocks * 1024 elems (4 per thread); also emits inv = 1/max(cnt,1)
__global__ __launch_bounds__(256) void k_scan1(const int* __restrict__ hist,
                                               int* __restrict__ offs,
                                               int* __restrict__ bsum,
                                               float* __restrict__ inv) {
    __shared__ int ts[256];
    int base = blockIdx.x * 1024 + threadIdx.x * 4;
    int4 v = *(const int4*)(hist + base);
    inv[base + 0] = 1.0f / (float)(v.x > 0 ? v.x : 1);
    inv[base + 1] = 1.0f / (float)(v.y > 0 ? v.y : 1);
    inv[base + 2] = 1.0f / (float)(v.z > 0 ? v.z : 1);
    inv[base + 3] = 1.0f / (float)(v.w > 0 ? v.w : 1);
    int s = v.x + v.y + v.z + v.w;
    ts[threadIdx.x] = s;
    __syncthreads();
    for (int ofs = 1; ofs < 256; ofs <<= 1) {
        int t = (threadIdx.x >= ofs) ? ts[threadIdx.x - ofs] : 0;
        __syncthreads();
        ts[threadIdx.x] += t;
        __syncthreads();
    }
    int excl = ts[threadIdx.x] - s;
    offs[base + 0] = excl;
    offs[base + 1] = excl + v.x;
    offs[base + 2] = excl + v.x + v.y;
    offs[base + 3] = excl + v.x + v.y + v.z;
    if (threadIdx.x == 255) bsum[blockIdx.x] = ts[255];
}

__global__ __launch_bounds__(256) void k_scan2(int* __restrict__ bsum) {
    __shared__ int ts[256];
    int v = bsum[threadIdx.x];
    ts[threadIdx.x] = v;
    __syncthreads();
    for (int ofs = 1; ofs < 256; ofs <<= 1) {
        int t = (threadIdx.x >= ofs) ? ts[threadIdx.x - ofs] : 0;
        __syncthreads();
        ts[threadIdx.x] += t;
        __syncthreads();
    }
    bsum[threadIdx.x] = ts[threadIdx.x] - v;   // exclusive
}

__global__ __launch_bounds__(256) void k_scan3(int* __restrict__ offs,
                                               const int* __restrict__ bsum,
                                               int* __restrict__ cursor) {
    int i = blockIdx.x * 256 + threadIdx.x;    // grid covers NRSEG
    int v = offs[i] + bsum[i >> 10];
    offs[i] = v;
    cursor[i] = v;
}

__global__ __launch_bounds__(256) void k_scatter(const int* __restrict__ ei,
                                                 const int* __restrict__ ea,
                                                 int* __restrict__ cursor,
                                                 unsigned* __restrict__ sorted) {
    int e = blockIdx.x * 256 + threadIdx.x;
    if (e < EE) {
        int src = ei[e];
        int dst = ei[EE + e];
        int a   = ea[e];
        int pos = atomicAdd(&cursor[a * NN + dst], 1);
        sorted[pos] = (unsigned)src;
    }
}

// ---------------- weight prep: transpose + split to bf16 hi/lo ----------------
// wt layout: mat = l*5 + {0=root, 1..4=rel r}; wt[mat*16384 + n*128 + k]

__global__ __launch_bounds__(256) void k_prep(const float* __restrict__ W_root,
                                              const float* __restrict__ W_rel,
                                              u16* __restrict__ wtH,
                                              u16* __restrict__ wtL) {
    int idx = blockIdx.x * 256 + threadIdx.x;   // grid covers 10*16384
    int mat = idx >> 14;
    int rem = idx & 16383;
    int n = rem >> 7, k = rem & 127;
    int l = mat / 5, m5 = mat - l * 5;
    float v = (m5 == 0) ? W_root[l * 16384 + k * 128 + n]
                        : W_rel[((l * RR + (m5 - 1)) * 128 + k) * 128 + n];
    u32 hi = bf16_rne(v);
    float fh = __uint_as_float(hi << 16);
    u32 lo = __float_as_uint(v - fh) >> 16;
    wtH[idx] = (u16)hi;
    wtL[idx] = (u16)lo;
}

// ---------------- embedding: h0 = bf16(x @ W_emb + b_emb) ----------------

__global__ __launch_bounds__(256, 2) void k_embed(const float* __restrict__ x,
                                                  const float* __restrict__ W,
                                                  const float* __restrict__ b,
                                                  u16* __restrict__ h) {
    __shared__ float sA[16 * 64];
    __shared__ float sB[16 * 128];
    int tid = threadIdx.x;
    int tx = tid & 31, ty = tid >> 5;
    int row0 = blockIdx.x * 64;

    float4 bv = *(const float4*)&b[tx * 4];
    float acc[8][4];
#pragma unroll
    for (int i = 0; i < 8; ++i) { acc[i][0]=bv.x; acc[i][1]=bv.y; acc[i][2]=bv.z; acc[i][3]=bv.w; }

    for (int kb = 0; kb < 4; ++kb) {
        {   // stage A: 64 rows x 16 k
            int rr = tid >> 2, kq = tid & 3;
            float4 v = *(const float4*)&x[(row0 + rr) * FIN + kb * 16 + kq * 4];
            sA[(kq*4+0)*64 + rr] = v.x;
            sA[(kq*4+1)*64 + rr] = v.y;
            sA[(kq*4+2)*64 + rr] = v.z;
            sA[(kq*4+3)*64 + rr] = v.w;
        }
#pragma unroll
        for (int i = 0; i < 2; ++i) {   // stage B: 16x128
            int f = tid + i * 256;
            *(float4*)&sB[f * 4] = *(const float4*)&W[kb * 16 * 128 + f * 4];
        }
        __syncthreads();
#pragma unroll
        for (int kk = 0; kk < 16; ++kk) {
            float4 a0 = *(const float4*)&sA[kk * 64 + ty * 4];
            float4 a1 = *(const float4*)&sA[kk * 64 + 32 + ty * 4];
            float4 bq = *(const float4*)&sB[kk * 128 + tx * 4];
            float ar[8] = {a0.x,a0.y,a0.z,a0.w,a1.x,a1.y,a1.z,a1.w};
#pragma unroll
            for (int i = 0; i < 8; ++i) {
                acc[i][0] = fmaf(ar[i], bq.x, acc[i][0]);
                acc[i][1] = fmaf(ar[i], bq.y, acc[i][1]);
                acc[i][2] = fmaf(ar[i], bq.z, acc[i][2]);
                acc[i][3] = fmaf(ar[i], bq.w, acc[i][3]);
            }
        }
        __syncthreads();
    }
#pragma unroll
    for (int i = 0; i < 8; ++i) {
        int row = (i < 4) ? (ty * 4 + i) : (32 + ty * 4 + (i - 4));
        u32 s0 = bf16_rne(acc[i][0]), s1 = bf16_rne(acc[i][1]);
        u32 s2 = bf16_rne(acc[i][2]), s3 = bf16_rne(acc[i][3]);
        *(uint2*)&h[(row0 + row) * DD + tx * 4] = make_uint2(s0 | (s1 << 16), s2 | (s3 << 16));
    }
}

// ---------------- fused RGCN layer (MFMA, LDS-staged B, bf16 h) ----------------
// h_out = relu( h @ Wroot + sum_r mean_r(h) @ Wrel_r + bias ); LAST fuses max-pool.
// 256 threads = 4 waves; wave owns a 16-node M-strip.
// LDS: fH (A frags, hi only, 16 KB wave-private) + sB (B chunk hi+lo 32 KB,
// unioned with gather index scratch) = 48 KB -> 3 blocks/CU.

template<int LAST>
__global__ __launch_bounds__(256, 3) void k_layer(const u16* __restrict__ hin,
                                                  u16* __restrict__ houtH,
                                                  float* __restrict__ outF,
                                                  const u16* __restrict__ wtH,
                                                  const u16* __restrict__ wtL,
                                                  const float* __restrict__ bias,
                                                  const unsigned* __restrict__ sorted,
                                                  const int* __restrict__ offs,
                                                  const float* __restrict__ inv) {
    __shared__ __align__(16) u16 fH[4 * 2048];   // 16 KB A-frags (swizzled, wave-private)
    __shared__ __align__(16) u16 sB[16384];      // 32 KB: B chunk (H at 0, L at +8192) / sIdx

    int tid  = threadIdx.x;
    int wave = tid >> 6, lane = tid & 63;
    int half = lane >> 5;            // gather: which node of the pair
    int qx   = lane & 31;            // gather: feature quad (cols qx*4..+3)
    int mm   = lane & 15;            // MFMA m/n lane index
    int quad = lane >> 4;            // MFMA quad
    int row0 = blockIdx.x * 64;
    int wbU  = wave * 2048;          // fH wave base (ushorts)
    int wb   = wave * 2048;          // sIdx wave base (ints; sB reinterpreted)
    int* sIdx = (int*)sB;

    f32x4 acc[8];
#pragma unroll
    for (int i = 0; i < 8; ++i) acc[i] = (f32x4){0.f, 0.f, 0.f, 0.f};

    // store 4 bf16 (packed uint2) into wave's swizzled A-frag slot
    auto writeFragU = [&](int m, uint2 u) {
        int kstep = qx >> 3, qd = (qx >> 1) & 3, par = qx & 1;
        int idx = ((kstep << 6) + (qd << 4) + (m ^ (qd | (kstep << 2)))) * 8 + par * 4;
        *(uint2*)&fH[wbU + idx] = u;
    };
    auto writeFrag = [&](int m, float4 v) {
        u32 h0 = bf16_rne(v.x), h1 = bf16_rne(v.y);
        u32 h2 = bf16_rne(v.z), h3 = bf16_rne(v.w);
        writeFragU(m, make_uint2(h0 | (h1 << 16), h2 | (h3 << 16)));
    };

    // stage B (k-half h, hi+lo) into sB, then MFMA those 2 k-chunks for all nt
    auto mfma_halves = [&](const u16* __restrict__ BH, const u16* __restrict__ BL,
                           const bf16x8* AH) {
#pragma unroll
        for (int h = 0; h < 2; ++h) {
#pragma unroll
            for (int i = 0; i < 4; ++i) {        // 16 KB per matrix-half per buffer
                int u = i * 256 + tid;
                int n = u >> 3, sub = u & 7;
                gl_lds16(BH + n * 128 + h * 64 + sub * 8, &sB[u * 8]);
                gl_lds16(BL + n * 128 + h * 64 + sub * 8, &sB[8192 + u * 8]);
            }
            __syncthreads();                     // DMA drained (vmcnt0 at barrier)
#pragma unroll
            for (int nt = 0; nt < 8; ++nt) {
#pragma unroll
                for (int ks2 = 0; ks2 < 2; ++ks2) {
                    int off = (nt * 16 + mm) * 64 + ks2 * 32 + quad * 8;
                    bf16x8 BHf = *(const bf16x8*)&sB[off];
                    bf16x8 BLf = *(const bf16x8*)&sB[8192 + off];
                    f32x4 a = acc[nt];
                    a = __builtin_amdgcn_mfma_f32_16x16x32_bf16(AH[h * 2 + ks2], BHf, a, 0, 0, 0);
                    a = __builtin_amdgcn_mfma_f32_16x16x32_bf16(AH[h * 2 + ks2], BLf, a, 0, 0, 0);
                    acc[nt] = a;
                }
            }
            __syncthreads();                     // protect sB before restage / sIdx use
        }
    };

    auto loadA = [&](bf16x8* AH) {
#pragma unroll
        for (int ks = 0; ks < 4; ++ks) {
            int off16 = ks * 64 + quad * 16 + (mm ^ (quad | (ks << 2)));
            AH[ks] = *(const bf16x8*)&fH[wbU + off16 * 8];
        }
    };

    // ---- Part 1: root term (A = hin strip, already bf16 -> zero conversion) ----
#pragma unroll
    for (int t2 = 0; t2 < 8; ++t2) {
        int m = t2 * 2 + half;
        uint2 u = *(const uint2*)&hin[(row0 + wave * 16 + m) * DD + qx * 4];
        writeFragU(m, u);
    }
    {
        bf16x8 AH[4];
        loadA(AH);
        mfma_halves(wtH, wtL, AH);
    }

    // ---- Part 2: per-relation mean-aggregate -> A frags -> MFMA ----
    for (int g = 0; g < RR; ++g) {
        int bidx0 = g * NN + row0 + wave * 16;
        int w0 = offs[bidx0];
        int i16 = bidx0 + 16;
        int w1 = (i16 < NRSEG) ? offs[i16] : EE;
        int wcnt = w1 - w0;

        if (wcnt <= 2048) {
            // prestage this wave's sorted-index range (coalesced), wave-private
            for (int i = lane; i < wcnt; i += 64) sIdx[wb + i] = (int)sorted[w0 + i];

            for (int t2 = 0; t2 < 8; ++t2) {     // 2 nodes in flight (half-waves)
                int m = t2 * 2 + half;
                int b = bidx0 + m;
                int r0 = offs[b];
                int r1 = (b + 1 < NRSEG) ? offs[b + 1] : EE;
                int o  = r0 - w0;
                int cnt = r1 - r0;
                float ax = 0.f, ay = 0.f, az = 0.f, aw = 0.f;
                int j = 0;
                for (; j + 8 <= cnt; j += 8) {
                    int i0 = sIdx[wb+o+j+0], i1 = sIdx[wb+o+j+1];
                    int i2 = sIdx[wb+o+j+2], i3 = sIdx[wb+o+j+3];
                    int i4 = sIdx[wb+o+j+4], i5 = sIdx[wb+o+j+5];
                    int i6 = sIdx[wb+o+j+6], i7 = sIdx[wb+o+j+7];
                    uint2 v0 = *(const uint2*)&hin[i0 * DD + qx * 4];
                    uint2 v1 = *(const uint2*)&hin[i1 * DD + qx * 4];
                    uint2 v2 = *(const uint2*)&hin[i2 * DD + qx * 4];
                    uint2 v3 = *(const uint2*)&hin[i3 * DD + qx * 4];
                    uint2 v4 = *(const uint2*)&hin[i4 * DD + qx * 4];
                    uint2 v5 = *(const uint2*)&hin[i5 * DD + qx * 4];
                    uint2 v6 = *(const uint2*)&hin[i6 * DD + qx * 4];
                    uint2 v7 = *(const uint2*)&hin[i7 * DD + qx * 4];
#pragma unroll
                    for (int q = 0; q < 8; ++q) {
                        uint2 vv = (q==0)?v0:(q==1)?v1:(q==2)?v2:(q==3)?v3:(q==4)?v4:(q==5)?v5:(q==6)?v6:v7;
                        ax += __uint_as_float(vv.x << 16);
                        ay += __uint_as_float(vv.x & 0xffff0000u);
                        az += __uint_as_float(vv.y << 16);
                        aw += __uint_as_float(vv.y & 0xffff0000u);
                    }
                }
                for (; j < cnt; ++j) {
                    int i0 = sIdx[wb+o+j];
                    uint2 vv = *(const uint2*)&hin[i0 * DD + qx * 4];
                    ax += __uint_as_float(vv.x << 16);
                    ay += __uint_as_float(vv.x & 0xffff0000u);
                    az += __uint_as_float(vv.y << 16);
                    aw += __uint_as_float(vv.y & 0xffff0000u);
                }
                float s = inv[b];
                writeFrag(m, make_float4(ax * s, ay * s, az * s, aw * s));
            }
        } else {
            // cold fallback: indices straight from global
            for (int t2 = 0; t2 < 8; ++t2) {
                int m = t2 * 2 + half;
                int b = bidx0 + m;
                int r0 = offs[b];
                int r1 = (b + 1 < NRSEG) ? offs[b + 1] : EE;
                float ax = 0.f, ay = 0.f, az = 0.f, aw = 0.f;
                for (int e = r0; e < r1; ++e) {
                    int i0 = (int)sorted[e];
                    uint2 vv = *(const uint2*)&hin[i0 * DD + qx * 4];
                    ax += __uint_as_float(vv.x << 16);
                    ay += __uint_as_float(vv.x & 0xffff0000u);
                    az += __uint_as_float(vv.y << 16);
                    aw += __uint_as_float(vv.y & 0xffff0000u);
                }
                float s = inv[b];
                writeFrag(m, make_float4(ax * s, ay * s, az * s, aw * s));
            }
        }
        __syncthreads();                         // gathers done; sB free for staging
        {
            bf16x8 AH[4];
            loadA(AH);
            mfma_halves(wtH + (1 + g) * 16384, wtL + (1 + g) * 16384, AH);
        }
    }

    // ---- epilogue ----
    float bvv[8];
#pragma unroll
    for (int nt = 0; nt < 8; ++nt) bvv[nt] = bias[nt * 16 + mm];

    if constexpr (LAST) {
        // fused graph max-pool: relu >= 0, so uint-punned atomicMax is order-correct
        int gidx = row0 >> 7;                    // 64-node blocks never straddle graphs
#pragma unroll
        for (int nt = 0; nt < 8; ++nt) {
            float v0 = acc[nt][0], v1 = acc[nt][1], v2 = acc[nt][2], v3 = acc[nt][3];
            float v = fmaxf(fmaxf(v0, v1), fmaxf(v2, v3)) + bvv[nt];
            v = fmaxf(v, 0.f);                   // relu(max) == max(relu) per column
            v = fmaxf(v, __shfl_xor(v, 16));     // combine the 4 quads (same col)
            v = fmaxf(v, __shfl_xor(v, 32));
            if (lane < 16)
                atomicMax((u32*)&outF[gidx * DD + nt * 16 + mm], __float_as_uint(v));
        }
    } else {
        // bounce C through (dead) fH slice to get coalesced bf16 row writes
        u16* fs = &fH[wbU];
#pragma unroll
        for (int nt = 0; nt < 8; ++nt)
#pragma unroll
            for (int r = 0; r < 4; ++r)
                fs[(quad * 4 + r) * 128 + nt * 16 + mm] =
                    (u16)bf16_rne(fmaxf(acc[nt][r] + bvv[nt], 0.f));
        uint4* dst = (uint4*)&houtH[(row0 + wave * 16) * DD];
        const uint4* src = (const uint4*)fs;
#pragma unroll
        for (int i = 0; i < 4; ++i) dst[i * 64 + lane] = src[i * 64 + lane];
    }
}

// ---------------- launch ----------------

extern "C" void kernel_launch(void* const* d_in, const int* in_sizes, int n_in,
                              void* d_out, int out_size, void* d_ws, size_t ws_size,
                              hipStream_t stream) {
    const float* x      = (const float*)d_in[0];
    const int*   ei     = (const int*)  d_in[1];
    const int*   ea     = (const int*)  d_in[2];
    const float* W_emb  = (const float*)d_in[3];
    const float* b_emb  = (const float*)d_in[4];
    const float* W_root = (const float*)d_in[5];
    const float* W_rel  = (const float*)d_in[6];
    const float* bias   = (const float*)d_in[7];
    float* out = (float*)d_out;

    char* p = (char*)d_ws;
    u16*      h0H    = (u16*)p;      p += (size_t)NN * DD * 2;      // 16.78 MB
    u16*      h1H    = (u16*)p;      p += (size_t)NN * DD * 2;      // 16.78 MB
    int*      hist   = (int*)p;      p += (size_t)NRSEG * 4;        // 1 MB
    float*    inv    = (float*)p;    p += (size_t)NRSEG * 4;        // 1 MB
    int*      offs   = (int*)p;      p += (size_t)NRSEG * 4;        // 1 MB
    int*      cursor = (int*)p;      p += (size_t)NRSEG * 4;        // 1 MB
    int*      bsum   = (int*)p;      p += 1024;
    unsigned* sorted = (unsigned*)p; p += (size_t)EE * 4;           // 6.29 MB
    u16*      wtH    = (u16*)p;      p += (size_t)10 * 16384 * 2;   // 0.33 MB
    u16*      wtL    = (u16*)p;      p += (size_t)10 * 16384 * 2;   // 0.33 MB

    hipMemsetAsync(hist, 0, (size_t)NRSEG * 4, stream);
    hipMemsetAsync(out, 0, (size_t)out_size * 4, stream);  // fused maxpool init (relu>=0)

    k_prep   <<<640, 256, 0, stream>>>(W_root, W_rel, wtH, wtL);
    k_embed  <<<NN / 64, 256, 0, stream>>>(x, W_emb, b_emb, h0H);
    k_hist   <<<EE / 256, 256, 0, stream>>>(ei, ea, hist);
    k_scan1  <<<256, 256, 0, stream>>>(hist, offs, bsum, inv);
    k_scan2  <<<1, 256, 0, stream>>>(bsum);
    k_scan3  <<<NRSEG / 256, 256, 0, stream>>>(offs, bsum, cursor);
    k_scatter<<<EE / 256, 256, 0, stream>>>(ei, ea, cursor, sorted);

    k_layer<0><<<NN / 64, 256, 0, stream>>>(h0H, h1H, nullptr,
                                            wtH, wtL, bias, sorted, offs, inv);
    k_layer<1><<<NN / 64, 256, 0, stream>>>(h1H, nullptr, out,
                                            wtH + 81920, wtL + 81920, bias + 128,
                                            sorted, offs, inv);
}

// Round 6
// 546.696 us; speedup vs baseline: 1.3443x; 1.0737x over previous
//
#include <hip/hip_runtime.h>

// Problem constants
constexpr int GG    = 512;          // graphs
constexpr int NPG   = 128;          // nodes per graph
constexpr int FIN   = 64;
constexpr int DD    = 128;
constexpr int RR    = 4;
constexpr int NN    = GG * NPG;     // 65536 nodes
constexpr int EE    = 1572864;      // edges
constexpr int NRSEG = NN * RR;      // 262144 segments (key = r*NN + dst)

typedef __attribute__((ext_vector_type(8))) short bf16x8;
typedef __attribute__((ext_vector_type(4))) float f32x4;
typedef unsigned short u16;
typedef unsigned int   u32;

__device__ __forceinline__ u32 bf16_rne(float x) {
    u32 u = __float_as_uint(x);
    return (u + 0x7FFFu + ((u >> 16) & 1u)) >> 16;
}

// async global->LDS DMA, 16 B per lane; LDS side must be uniform-base + lane*16
__device__ __forceinline__ void gl_lds16(const void* g, void* l) {
    __builtin_amdgcn_global_load_lds((const __attribute__((address_space(1))) u32*)g,
                                     (__attribute__((address_space(3))) u32*)l, 16, 0, 0);
}

// ---------------- sort pipeline ----------------

__global__ __launch_bounds__(256) void k_hist(const int* __restrict__ ei,
                                              const int* __restrict__ ea,
                                              int* __restrict__ hist) {
    int e = blockIdx.x * 256 + threadIdx.x;
    if (e < EE) {
        int dst = ei[EE + e];
        int a   = ea[e];
        atomicAdd(&hist[a * NN + dst], 1);
    }
}

// 262144 = 256 blocks * 1024 elems (4 per thread); also emits inv = 1/max(cnt,1)
__global__ __launch_bounds__(256) void k_scan1(const int* __restrict__ hist,
                                               int* __restrict__ offs,
                                               int* __restrict__ bsum,
                                               float* __restrict__ inv) {
    __shared__ int ts[256];
    int base = blockIdx.x * 1024 + threadIdx.x * 4;
    int4 v = *(const int4*)(hist + base);
    inv[base + 0] = 1.0f / (float)(v.x > 0 ? v.x : 1);
    inv[base + 1] = 1.0f / (float)(v.y > 0 ? v.y : 1);
    inv[base + 2] = 1.0f / (float)(v.z > 0 ? v.z : 1);
    inv[base + 3] = 1.0f / (float)(v.w > 0 ? v.w : 1);
    int s = v.x + v.y + v.z + v.w;
    ts[threadIdx.x] = s;
    __syncthreads();
    for (int ofs = 1; ofs < 256; ofs <<= 1) {
        int t = (threadIdx.x >= ofs) ? ts[threadIdx.x - ofs] : 0;
        __syncthreads();
        ts[threadIdx.x] += t;
        __syncthreads();
    }
    int excl = ts[threadIdx.x] - s;
    offs[base + 0] = excl;
    offs[base + 1] = excl + v.x;
    offs[base + 2] = excl + v.x + v.y;
    offs[base + 3] = excl + v.x + v.y + v.z;
    if (threadIdx.x == 255) bsum[blockIdx.x] = ts[255];
}

__global__ __launch_bounds__(256) void k_scan2(int* __restrict__ bsum) {
    __shared__ int ts[256];
    int v = bsum[threadIdx.x];
    ts[threadIdx.x] = v;
    __syncthreads();
    for (int ofs = 1; ofs < 256; ofs <<= 1) {
        int t = (threadIdx.x >= ofs) ? ts[threadIdx.x - ofs] : 0;
        __syncthreads();
        ts[threadIdx.x] += t;
        __syncthreads();
    }
    bsum[threadIdx.x] = ts[threadIdx.x] - v;   // exclusive
}

__global__ __launch_bounds__(256) void k_scan3(int* __restrict__ offs,
                                               const int* __restrict__ bsum,
                                               int* __restrict__ cursor) {
    int i = blockIdx.x * 256 + threadIdx.x;    // grid covers NRSEG
    int v = offs[i] + bsum[i >> 10];
    offs[i] = v;
    cursor[i] = v;
}

__global__ __launch_bounds__(256) void k_scatter(const int* __restrict__ ei,
                                                 const int* __restrict__ ea,
                                                 int* __restrict__ cursor,
                                                 unsigned* __restrict__ sorted) {
    int e = blockIdx.x * 256 + threadIdx.x;
    if (e < EE) {
        int src = ei[e];
        int dst = ei[EE + e];
        int a   = ea[e];
        int pos = atomicAdd(&cursor[a * NN + dst], 1);
        sorted[pos] = (unsigned)src;
    }
}

// ---------------- weight prep: transpose to bf16 (hi only) ----------------
// wt layout: mat = l*5 + {0=root, 1..4=rel r}; wt[mat*16384 + n*128 + k]

__global__ __launch_bounds__(256) void k_prep(const float* __restrict__ W_root,
                                              const float* __restrict__ W_rel,
                                              u16* __restrict__ wtH) {
    int idx = blockIdx.x * 256 + threadIdx.x;   // grid covers 10*16384
    int mat = idx >> 14;
    int rem = idx & 16383;
    int n = rem >> 7, k = rem & 127;
    int l = mat / 5, m5 = mat - l * 5;
    float v = (m5 == 0) ? W_root[l * 16384 + k * 128 + n]
                        : W_rel[((l * RR + (m5 - 1)) * 128 + k) * 128 + n];
    wtH[idx] = (u16)bf16_rne(v);
}

// ---------------- embedding: h0 = bf16(x @ W_emb + b_emb) ----------------

__global__ __launch_bounds__(256, 2) void k_embed(const float* __restrict__ x,
                                                  const float* __restrict__ W,
                                                  const float* __restrict__ b,
                                                  u16* __restrict__ h) {
    __shared__ float sA[16 * 64];
    __shared__ float sB[16 * 128];
    int tid = threadIdx.x;
    int tx = tid & 31, ty = tid >> 5;
    int row0 = blockIdx.x * 64;

    float4 bv = *(const float4*)&b[tx * 4];
    float acc[8][4];
#pragma unroll
    for (int i = 0; i < 8; ++i) { acc[i][0]=bv.x; acc[i][1]=bv.y; acc[i][2]=bv.z; acc[i][3]=bv.w; }

    for (int kb = 0; kb < 4; ++kb) {
        {   // stage A: 64 rows x 16 k
            int rr = tid >> 2, kq = tid & 3;
            float4 v = *(const float4*)&x[(row0 + rr) * FIN + kb * 16 + kq * 4];
            sA[(kq*4+0)*64 + rr] = v.x;
            sA[(kq*4+1)*64 + rr] = v.y;
            sA[(kq*4+2)*64 + rr] = v.z;
            sA[(kq*4+3)*64 + rr] = v.w;
        }
#pragma unroll
        for (int i = 0; i < 2; ++i) {   // stage B: 16x128
            int f = tid + i * 256;
            *(float4*)&sB[f * 4] = *(const float4*)&W[kb * 16 * 128 + f * 4];
        }
        __syncthreads();
#pragma unroll
        for (int kk = 0; kk < 16; ++kk) {
            float4 a0 = *(const float4*)&sA[kk * 64 + ty * 4];
            float4 a1 = *(const float4*)&sA[kk * 64 + 32 + ty * 4];
            float4 bq = *(const float4*)&sB[kk * 128 + tx * 4];
            float ar[8] = {a0.x,a0.y,a0.z,a0.w,a1.x,a1.y,a1.z,a1.w};
#pragma unroll
            for (int i = 0; i < 8; ++i) {
                acc[i][0] = fmaf(ar[i], bq.x, acc[i][0]);
                acc[i][1] = fmaf(ar[i], bq.y, acc[i][1]);
                acc[i][2] = fmaf(ar[i], bq.z, acc[i][2]);
                acc[i][3] = fmaf(ar[i], bq.w, acc[i][3]);
            }
        }
        __syncthreads();
    }
#pragma unroll
    for (int i = 0; i < 8; ++i) {
        int row = (i < 4) ? (ty * 4 + i) : (32 + ty * 4 + (i - 4));
        u32 s0 = bf16_rne(acc[i][0]), s1 = bf16_rne(acc[i][1]);
        u32 s2 = bf16_rne(acc[i][2]), s3 = bf16_rne(acc[i][3]);
        *(uint2*)&h[(row0 + row) * DD + tx * 4] = make_uint2(s0 | (s1 << 16), s2 | (s3 << 16));
    }
}

// ---------------- fused RGCN layer (MFMA, dbuf-B, swizzled, bf16 h+W) --------
// h_out = relu( h @ Wroot + sum_r mean_r(h) @ Wrel_r + bias ); LAST fuses max-pool.
// 256 threads = 4 waves; wave owns a 16-node M-strip.
// B tile (16 KB = one k-half of one 128x128 bf16 mat) is XOR-swizzled:
// granule (n,j) lives at LDS slot n*8 + (j^(n&7)) -> b128 reads hit 8 distinct
// bank-quads within each 8-lane phase (conflict-free). Double-buffered; DMA for
// buf is issued a phase early (hidden behind gather / the other half's MFMA).
// LDS: fH 16K + sBuf 32K + sIdx 4K = 53248 B -> 3 blocks/CU.

template<int LAST>
__global__ __launch_bounds__(256, 3) void k_layer(const u16* __restrict__ hin,
                                                  u16* __restrict__ houtH,
                                                  float* __restrict__ outF,
                                                  const u16* __restrict__ wtH,
                                                  const float* __restrict__ bias,
                                                  const unsigned* __restrict__ sorted,
                                                  const int* __restrict__ offs,
                                                  const float* __restrict__ inv) {
    __shared__ __align__(16) u16 fH[4 * 2048];     // 16 KB A-frags (swizzled, wave-private)
    __shared__ __align__(16) u16 sBuf[2][8192];    // 2 x 16 KB B half-mat buffers
    __shared__ int sIdx[4 * 256];                  // 4 KB gather index scratch

    int tid  = threadIdx.x;
    int wave = tid >> 6, lane = tid & 63;
    int half = lane >> 5;            // gather: which node of the pair
    int qx   = lane & 31;            // gather: feature quad (cols qx*4..+3)
    int mm   = lane & 15;            // MFMA m/n lane index
    int quad = lane >> 4;            // MFMA quad
    int row0 = blockIdx.x * 64;
    int wbU  = wave * 2048;          // fH wave base (ushorts)
    int wb   = wave * 256;           // sIdx wave base (ints)

    f32x4 acc[8];
#pragma unroll
    for (int i = 0; i < 8; ++i) acc[i] = (f32x4){0.f, 0.f, 0.f, 0.f};

    // store 4 bf16 (packed uint2) into wave's swizzled A-frag slot
    auto writeFragU = [&](int m, uint2 u) {
        int kstep = qx >> 3, qd = (qx >> 1) & 3, par = qx & 1;
        int idx = ((kstep << 6) + (qd << 4) + (m ^ (qd | (kstep << 2)))) * 8 + par * 4;
        *(uint2*)&fH[wbU + idx] = u;
    };
    auto writeFrag = [&](int m, float4 v) {
        u32 h0 = bf16_rne(v.x), h1 = bf16_rne(v.y);
        u32 h2 = bf16_rne(v.z), h3 = bf16_rne(v.w);
        writeFragU(m, make_uint2(h0 | (h1 << 16), h2 | (h3 << 16)));
    };

    // issue DMA of one k-half (16 KB) of matrix `Bh` into sBuf[bufi], swizzled
    auto stage = [&](const u16* __restrict__ Bh, int bufi) {
#pragma unroll
        for (int i = 0; i < 4; ++i) {
            int u = i * 256 + tid;
            int n = u >> 3, jj = u & 7;
            gl_lds16(Bh + n * 128 + (jj ^ (n & 7)) * 8, &sBuf[bufi][u * 8]);
        }
    };

    // MFMA one staged k-half against two A k-chunks
    auto mfma_half = [&](int bufi, bf16x8 A0, bf16x8 A1) {
        const u16* buf = sBuf[bufi];
#pragma unroll
        for (int nt = 0; nt < 8; ++nt) {
            int n = nt * 16 + mm;
            int g0 = n * 8 + (quad ^ (n & 7));
            int g1 = n * 8 + ((4 + quad) ^ (n & 7));
            bf16x8 B0 = *(const bf16x8*)&buf[g0 * 8];
            bf16x8 B1 = *(const bf16x8*)&buf[g1 * 8];
            f32x4 a = acc[nt];
            a = __builtin_amdgcn_mfma_f32_16x16x32_bf16(A0, B0, a, 0, 0, 0);
            a = __builtin_amdgcn_mfma_f32_16x16x32_bf16(A1, B1, a, 0, 0, 0);
            acc[nt] = a;
        }
    };

    auto loadA = [&](bf16x8* AH) {
#pragma unroll
        for (int ks = 0; ks < 4; ++ks) {
            int off16 = ks * 64 + quad * 16 + (mm ^ (quad | (ks << 2)));
            AH[ks] = *(const bf16x8*)&fH[wbU + off16 * 8];
        }
    };

    // per-relation mean-aggregate for this wave's 16 nodes -> fH
    auto gather = [&](int g) {
        int bidx0 = g * NN + row0 + wave * 16;
        int w0 = offs[bidx0];
        int i16 = bidx0 + 16;
        int w1 = (i16 < NRSEG) ? offs[i16] : EE;
        int wcnt = w1 - w0;

        if (wcnt <= 256) {
            for (int i = lane; i < wcnt; i += 64) sIdx[wb + i] = (int)sorted[w0 + i];
            for (int t2 = 0; t2 < 8; ++t2) {     // 2 nodes in flight (half-waves)
                int m2 = t2 * 2 + half;
                int b = bidx0 + m2;
                int r0 = offs[b];
                int r1 = (b + 1 < NRSEG) ? offs[b + 1] : EE;
                int o  = r0 - w0;
                int cnt = r1 - r0;
                float ax = 0.f, ay = 0.f, az = 0.f, aw = 0.f;
                int j = 0;
                for (; j + 8 <= cnt; j += 8) {
                    int i0 = sIdx[wb+o+j+0], i1 = sIdx[wb+o+j+1];
                    int i2 = sIdx[wb+o+j+2], i3 = sIdx[wb+o+j+3];
                    int i4 = sIdx[wb+o+j+4], i5 = sIdx[wb+o+j+5];
                    int i6 = sIdx[wb+o+j+6], i7 = sIdx[wb+o+j+7];
                    uint2 v0 = *(const uint2*)&hin[i0 * DD + qx * 4];
                    uint2 v1 = *(const uint2*)&hin[i1 * DD + qx * 4];
                    uint2 v2 = *(const uint2*)&hin[i2 * DD + qx * 4];
                    uint2 v3 = *(const uint2*)&hin[i3 * DD + qx * 4];
                    uint2 v4 = *(const uint2*)&hin[i4 * DD + qx * 4];
                    uint2 v5 = *(const uint2*)&hin[i5 * DD + qx * 4];
                    uint2 v6 = *(const uint2*)&hin[i6 * DD + qx * 4];
                    uint2 v7 = *(const uint2*)&hin[i7 * DD + qx * 4];
#pragma unroll
                    for (int q = 0; q < 8; ++q) {
                        uint2 vv = (q==0)?v0:(q==1)?v1:(q==2)?v2:(q==3)?v3:(q==4)?v4:(q==5)?v5:(q==6)?v6:v7;
                        ax += __uint_as_float(vv.x << 16);
                        ay += __uint_as_float(vv.x & 0xffff0000u);
                        az += __uint_as_float(vv.y << 16);
                        aw += __uint_as_float(vv.y & 0xffff0000u);
                    }
                }
                for (; j < cnt; ++j) {
                    int i0 = sIdx[wb+o+j];
                    uint2 vv = *(const uint2*)&hin[i0 * DD + qx * 4];
                    ax += __uint_as_float(vv.x << 16);
                    ay += __uint_as_float(vv.x & 0xffff0000u);
                    az += __uint_as_float(vv.y << 16);
                    aw += __uint_as_float(vv.y & 0xffff0000u);
                }
                float s = inv[b];
                writeFrag(m2, make_float4(ax * s, ay * s, az * s, aw * s));
            }
        } else {
            // cold fallback: indices straight from global
            for (int t2 = 0; t2 < 8; ++t2) {
                int m2 = t2 * 2 + half;
                int b = bidx0 + m2;
                int r0 = offs[b];
                int r1 = (b + 1 < NRSEG) ? offs[b + 1] : EE;
                float ax = 0.f, ay = 0.f, az = 0.f, aw = 0.f;
                for (int e = r0; e < r1; ++e) {
                    int i0 = (int)sorted[e];
                    uint2 vv = *(const uint2*)&hin[i0 * DD + qx * 4];
                    ax += __uint_as_float(vv.x << 16);
                    ay += __uint_as_float(vv.x & 0xffff0000u);
                    az += __uint_as_float(vv.y << 16);
                    aw += __uint_as_float(vv.y & 0xffff0000u);
                }
                float s = inv[b];
                writeFrag(m2, make_float4(ax * s, ay * s, az * s, aw * s));
            }
        }
    };

    // ---- prologue: stage mat0 half0; build root A from hin (already bf16) ----
    stage(wtH, 0);
#pragma unroll
    for (int t2 = 0; t2 < 8; ++t2) {
        int m2 = t2 * 2 + half;
        uint2 u = *(const uint2*)&hin[(row0 + wave * 16 + m2) * DD + qx * 4];
        writeFragU(m2, u);
    }
    __syncthreads();                             // buf0 ready (all waves' DMA drained)

    // ---- 5 matrices: mat0 = root (A from hin), mat 1..4 = rel 0..3 ----
    for (int m = 0; m < 5; ++m) {
        bf16x8 AH[4];
        loadA(AH);
        stage(wtH + m * 16384 + 64, 1);          // k-half 1 of mat m -> buf1
        mfma_half(0, AH[0], AH[1]);              // k-half 0
        __syncthreads();                         // buf1 ready; buf0 free
        if (m < 4) {
            stage(wtH + (m + 1) * 16384, 0);     // k-half 0 of next mat -> buf0
            gather(m);                           // overwrites fH (AH already in regs)
        }
        mfma_half(1, AH[2], AH[3]);              // k-half 1
        if (m < 4) __syncthreads();              // buf0 ready; buf1 free for next stage
    }

    // ---- epilogue ----
    float bvv[8];
#pragma unroll
    for (int nt = 0; nt < 8; ++nt) bvv[nt] = bias[nt * 16 + mm];

    if constexpr (LAST) {
        // fused graph max-pool: relu >= 0, so uint-punned atomicMax is order-correct
        int gidx = row0 >> 7;                    // 64-node blocks never straddle graphs
#pragma unroll
        for (int nt = 0; nt < 8; ++nt) {
            float v0 = acc[nt][0], v1 = acc[nt][1], v2 = acc[nt][2], v3 = acc[nt][3];
            float v = fmaxf(fmaxf(v0, v1), fmaxf(v2, v3)) + bvv[nt];
            v = fmaxf(v, 0.f);                   // relu(max) == max(relu) per column
            v = fmaxf(v, __shfl_xor(v, 16));     // combine the 4 quads (same col)
            v = fmaxf(v, __shfl_xor(v, 32));
            if (lane < 16)
                atomicMax((u32*)&outF[gidx * DD + nt * 16 + mm], __float_as_uint(v));
        }
    } else {
        // bounce C through (dead) fH slice to get coalesced bf16 row writes
        u16* fs = &fH[wbU];
#pragma unroll
        for (int nt = 0; nt < 8; ++nt)
#pragma unroll
            for (int r = 0; r < 4; ++r)
                fs[(quad * 4 + r) * 128 + nt * 16 + mm] =
                    (u16)bf16_rne(fmaxf(acc[nt][r] + bvv[nt], 0.f));
        uint4* dst = (uint4*)&houtH[(row0 + wave * 16) * DD];
        const uint4* src = (const uint4*)fs;
#pragma unroll
        for (int i = 0; i < 4; ++i) dst[i * 64 + lane] = src[i * 64 + lane];
    }
}

// ---------------- launch ----------------

extern "C" void kernel_launch(void* const* d_in, const int* in_sizes, int n_in,
                              void* d_out, int out_size, void* d_ws, size_t ws_size,
                              hipStream_t stream) {
    const float* x      = (const float*)d_in[0];
    const int*   ei     = (const int*)  d_in[1];
    const int*   ea     = (const int*)  d_in[2];
    const float* W_emb  = (const float*)d_in[3];
    const float* b_emb  = (const float*)d_in[4];
    const float* W_root = (const float*)d_in[5];
    const float* W_rel  = (const float*)d_in[6];
    const float* bias   = (const float*)d_in[7];
    float* out = (float*)d_out;

    char* p = (char*)d_ws;
    u16*      h0H    = (u16*)p;      p += (size_t)NN * DD * 2;      // 16.78 MB
    u16*      h1H    = (u16*)p;      p += (size_t)NN * DD * 2;      // 16.78 MB
    int*      hist   = (int*)p;      p += (size_t)NRSEG * 4;        // 1 MB
    float*    inv    = (float*)p;    p += (size_t)NRSEG * 4;        // 1 MB
    int*      offs   = (int*)p;      p += (size_t)NRSEG * 4;        // 1 MB
    int*      cursor = (int*)p;      p += (size_t)NRSEG * 4;        // 1 MB
    int*      bsum   = (int*)p;      p += 1024;
    unsigned* sorted = (unsigned*)p; p += (size_t)EE * 4;           // 6.29 MB
    u16*      wtH    = (u16*)p;      p += (size_t)10 * 16384 * 2;   // 0.33 MB

    hipMemsetAsync(hist, 0, (size_t)NRSEG * 4, stream);
    hipMemsetAsync(out, 0, (size_t)out_size * 4, stream);  // fused maxpool init (relu>=0)

    k_prep   <<<640, 256, 0, stream>>>(W_root, W_rel, wtH);
    k_embed  <<<NN / 64, 256, 0, stream>>>(x, W_emb, b_emb, h0H);
    k_hist   <<<EE / 256, 256, 0, stream>>>(ei, ea, hist);
    k_scan1  <<<256, 256, 0, stream>>>(hist, offs, bsum, inv);
    k_scan2  <<<1, 256, 0, stream>>>(bsum);
    k_scan3  <<<NRSEG / 256, 256, 0, stream>>>(offs, bsum, cursor);
    k_scatter<<<EE / 256, 256, 0, stream>>>(ei, ea, cursor, sorted);

    k_layer<0><<<NN / 64, 256, 0, stream>>>(h0H, h1H, nullptr,
                                            wtH, bias, sorted, offs, inv);
    k_layer<1><<<NN / 64, 256, 0, stream>>>(h1H, nullptr, out,
                                            wtH + 81920, bias + 128,
                                            sorted, offs, inv);
}

// Round 8
// 419.247 us; speedup vs baseline: 1.7530x; 1.3040x over previous
//
#include <hip/hip_runtime.h>

// Problem constants
constexpr int GG    = 512;          // graphs
constexpr int NPG   = 128;          // nodes per graph
constexpr int FIN   = 64;
constexpr int DD    = 128;
constexpr int RR    = 4;
constexpr int NN    = GG * NPG;     // 65536 nodes
constexpr int EE    = 1572864;      // edges
constexpr int NRSEG = NN * RR;      // 262144 segments (key = r*NN + dst)

typedef __attribute__((ext_vector_type(8))) short bf16x8;
typedef __attribute__((ext_vector_type(4))) float f32x4;
typedef unsigned short u16;
typedef unsigned int   u32;
typedef unsigned long long u64;

__device__ __forceinline__ u32 bf16_rne(float x) {
    u32 u = __float_as_uint(x);
    return (u + 0x7FFFu + ((u >> 16) & 1u)) >> 16;
}

// async global->LDS DMA, 16 B per lane; LDS side must be uniform-base + lane*16
__device__ __forceinline__ void gl_lds16(const void* g, void* l) {
    __builtin_amdgcn_global_load_lds((const __attribute__((address_space(1))) u32*)g,
                                     (__attribute__((address_space(3))) u32*)l, 16, 0, 0);
}

// ---------------- fused front: prep + embed + hist + out-zero ----------------
// blocks [0,1024): embed | [1024,7168): hist | [7168,7808): prep | [7808,7872): zero out
// NOTE: zero-out branch must cover ALL GG*DD floats (float4/thread) — the
// harness re-poisons d_out to 0xAA before every replay, and uint-punned
// atomicMax keeps poison (huge unsigned) if any element is left unzeroed.

__global__ __launch_bounds__(256, 2) void k_front(const float* __restrict__ x,
                                                  const float* __restrict__ W_emb,
                                                  const float* __restrict__ b_emb,
                                                  u16* __restrict__ h,
                                                  const int* __restrict__ ei,
                                                  const int* __restrict__ ea,
                                                  int* __restrict__ hist,
                                                  const float* __restrict__ W_root,
                                                  const float* __restrict__ W_rel,
                                                  u16* __restrict__ wtH,
                                                  float* __restrict__ outF) {
    __shared__ float sA[16 * 64];
    __shared__ float sB[16 * 128];
    int tid = threadIdx.x;
    int bid = blockIdx.x;

    if (bid < 1024) {
        // ---- embed: h = bf16(x @ W_emb + b_emb) ----
        int tx = tid & 31, ty = tid >> 5;
        int row0 = bid * 64;
        float4 bv = *(const float4*)&b_emb[tx * 4];
        float acc[8][4];
#pragma unroll
        for (int i = 0; i < 8; ++i) { acc[i][0]=bv.x; acc[i][1]=bv.y; acc[i][2]=bv.z; acc[i][3]=bv.w; }
        for (int kb = 0; kb < 4; ++kb) {
            {
                int rr = tid >> 2, kq = tid & 3;
                float4 v = *(const float4*)&x[(row0 + rr) * FIN + kb * 16 + kq * 4];
                sA[(kq*4+0)*64 + rr] = v.x;
                sA[(kq*4+1)*64 + rr] = v.y;
                sA[(kq*4+2)*64 + rr] = v.z;
                sA[(kq*4+3)*64 + rr] = v.w;
            }
#pragma unroll
            for (int i = 0; i < 2; ++i) {
                int f = tid + i * 256;
                *(float4*)&sB[f * 4] = *(const float4*)&W_emb[kb * 16 * 128 + f * 4];
            }
            __syncthreads();
#pragma unroll
            for (int kk = 0; kk < 16; ++kk) {
                float4 a0 = *(const float4*)&sA[kk * 64 + ty * 4];
                float4 a1 = *(const float4*)&sA[kk * 64 + 32 + ty * 4];
                float4 bq = *(const float4*)&sB[kk * 128 + tx * 4];
                float ar[8] = {a0.x,a0.y,a0.z,a0.w,a1.x,a1.y,a1.z,a1.w};
#pragma unroll
                for (int i = 0; i < 8; ++i) {
                    acc[i][0] = fmaf(ar[i], bq.x, acc[i][0]);
                    acc[i][1] = fmaf(ar[i], bq.y, acc[i][1]);
                    acc[i][2] = fmaf(ar[i], bq.z, acc[i][2]);
                    acc[i][3] = fmaf(ar[i], bq.w, acc[i][3]);
                }
            }
            __syncthreads();
        }
#pragma unroll
        for (int i = 0; i < 8; ++i) {
            int row = (i < 4) ? (ty * 4 + i) : (32 + ty * 4 + (i - 4));
            u32 s0 = bf16_rne(acc[i][0]), s1 = bf16_rne(acc[i][1]);
            u32 s2 = bf16_rne(acc[i][2]), s3 = bf16_rne(acc[i][3]);
            *(uint2*)&h[(row0 + row) * DD + tx * 4] = make_uint2(s0 | (s1 << 16), s2 | (s3 << 16));
        }
    } else if (bid < 7168) {
        // ---- hist ----
        int e = (bid - 1024) * 256 + tid;      // covers EE exactly
        int dst = ei[EE + e];
        int a   = ea[e];
        atomicAdd(&hist[a * NN + dst], 1);
    } else if (bid < 7808) {
        // ---- prep: transpose weights to bf16, wt[mat*16384 + n*128 + k] ----
        int idx = (bid - 7168) * 256 + tid;    // covers 10*16384
        int mat = idx >> 14;
        int rem = idx & 16383;
        int n = rem >> 7, k = rem & 127;
        int l = mat / 5, m5 = mat - l * 5;
        float v = (m5 == 0) ? W_root[l * 16384 + k * 128 + n]
                            : W_rel[((l * RR + (m5 - 1)) * 128 + k) * 128 + n];
        wtH[idx] = (u16)bf16_rne(v);
    } else {
        // ---- zero out (fused maxpool init; relu >= 0): float4 covers GG*DD ----
        int i = (bid - 7808) * 256 + tid;      // 16384 threads x 4 floats = 65536
        *(float4*)&outF[i * 4] = make_float4(0.f, 0.f, 0.f, 0.f);
    }
}

// ---------------- single-pass scan (decoupled lookback, 256 tiles) -----------
// Replaces scan1+scan2+scan3. Ticket order = acquire order; partial published
// before any wait -> no dispatch-order assumption, deadlock-free.

__global__ __launch_bounds__(256) void k_scan(const int* __restrict__ hist,
                                              int* __restrict__ offs,
                                              int* __restrict__ cursor,
                                              float* __restrict__ inv,
                                              u32* __restrict__ ticket,
                                              u64* __restrict__ stat) {
    __shared__ int ts[256];
    __shared__ int sh[2];
    int tid = threadIdx.x;
    if (tid == 0) sh[0] = (int)atomicAdd(ticket, 1u);
    __syncthreads();
    int tile = sh[0];

    int base = tile * 1024 + tid * 4;
    int4 v = *(const int4*)(hist + base);
    float4 iv;
    iv.x = 1.0f / (float)(v.x > 0 ? v.x : 1);
    iv.y = 1.0f / (float)(v.y > 0 ? v.y : 1);
    iv.z = 1.0f / (float)(v.z > 0 ? v.z : 1);
    iv.w = 1.0f / (float)(v.w > 0 ? v.w : 1);
    *(float4*)&inv[base] = iv;

    int s = v.x + v.y + v.z + v.w;
    ts[tid] = s;
    __syncthreads();
    for (int ofs = 1; ofs < 256; ofs <<= 1) {
        int t = (tid >= ofs) ? ts[tid - ofs] : 0;
        __syncthreads();
        ts[tid] += t;
        __syncthreads();
    }
    int total = ts[255];

    if (tid == 0)                              // publish partial before any wait
        atomicExch(&stat[tile], (1ull << 62) | (u64)(u32)total);

    if (tid < 64) {                            // wave-parallel lookback
        int lane = tid;
        int ex = 0;
        int t = tile - 1;
        while (t >= 0) {
            int idx = t - lane;
            int st; u32 val;
            if (idx >= 0) {
                u64 w;
                do {
                    w = atomicAdd(&stat[idx], 0ull);
                    st = (int)(w >> 62);
                    if (!st) __builtin_amdgcn_s_sleep(1);
                } while (!st);
                val = (u32)(w & 0xFFFFFFFFull);
            } else { st = 2; val = 0; }        // virtual prefix-0 below tile 0
            u64 ball = __ballot(st == 2);
            int p = (ball != 0) ? (__ffsll((long long)ball) - 1) : -1;
            int contrib = (p < 0 || lane <= p) ? (int)val : 0;
#pragma unroll
            for (int o = 32; o > 0; o >>= 1) contrib += __shfl_down(contrib, o);
            contrib = __shfl(contrib, 0);
            ex += contrib;
            if (p >= 0) break;
            t -= 64;
        }
        if (lane == 0) {
            sh[1] = ex;
            atomicExch(&stat[tile], (2ull << 62) | (u64)(u32)(ex + total));
        }
    }
    __syncthreads();

    int b0 = sh[1];
    int excl = ts[tid] - s + b0;
    int4 o4;
    o4.x = excl;
    o4.y = excl + v.x;
    o4.z = excl + v.x + v.y;
    o4.w = excl + v.x + v.y + v.z;
    *(int4*)&offs[base]   = o4;
    *(int4*)&cursor[base] = o4;
}

__global__ __launch_bounds__(256) void k_scatter(const int* __restrict__ ei,
                                                 const int* __restrict__ ea,
                                                 int* __restrict__ cursor,
                                                 unsigned* __restrict__ sorted) {
    int e = blockIdx.x * 256 + threadIdx.x;
    if (e < EE) {
        int src = ei[e];
        int dst = ei[EE + e];
        int a   = ea[e];
        int pos = atomicAdd(&cursor[a * NN + dst], 1);
        sorted[pos] = (unsigned)src;
    }
}

// ---------------- fused RGCN layer ----------------
// 256 threads = 4 waves; wave owns a 16-node M-strip.
// Gather: quarter-wave (16 lanes/node, uint4 16B/lane, 4 chains in flight).
// B staged in k-quarters (8 KB), double-buffered, XOR-swizzled (conflict-free).
// LDS: fH 16K + sQ 16K + sIdx 4K = 36864 B -> 4 blocks/CU.

template<int LAST>
__global__ __launch_bounds__(256, 4) void k_layer(const u16* __restrict__ hin,
                                                  u16* __restrict__ houtH,
                                                  float* __restrict__ outF,
                                                  const u16* __restrict__ wtH,
                                                  const float* __restrict__ bias,
                                                  const unsigned* __restrict__ sorted,
                                                  const int* __restrict__ offs,
                                                  const float* __restrict__ inv) {
    __shared__ __align__(16) u16 fH[4 * 2048];   // 16 KB A-frags (swizzled, wave-private)
    __shared__ __align__(16) u16 sQ[2][4096];    // 2 x 8 KB B k-quarter buffers
    __shared__ int sIdx[4 * 256];                // 4 KB gather index scratch

    int tid  = threadIdx.x;
    int wave = tid >> 6, lane = tid & 63;
    int mm   = lane & 15;            // MFMA m/n lane; gather col-octet
    int qd   = lane >> 4;            // MFMA quad; gather quarter (node group)
    int row0 = blockIdx.x * 64;
    int wbU  = wave * 2048;          // fH wave base (u16)
    int wb   = wave * 256;           // sIdx wave base (ints)

    f32x4 acc[8];
#pragma unroll
    for (int i = 0; i < 8; ++i) acc[i] = (f32x4){0.f, 0.f, 0.f, 0.f};

    // granule slot for A-frag: f(node, ks, g) = ks*64 + g*16 + (node ^ (ks*4+g))
    auto writeFragQ = [&](int node, uint4 u) {   // lane's cols = mm*8..+7
        int ks = mm >> 2, g = mm & 3;
        int slot = ks * 64 + g * 16 + (node ^ (ks * 4 + g));
        *(uint4*)&fH[wbU + slot * 8] = u;
    };
    auto loadA = [&](bf16x8* AH) {
#pragma unroll
        for (int ks = 0; ks < 4; ++ks) {
            int slot = ks * 64 + qd * 16 + (mm ^ (ks * 4 + qd));
            AH[ks] = *(const bf16x8*)&fH[wbU + slot * 8];
        }
    };

    // stage k-quarter `step` (mat step>>2, cols (step&3)*32..) into sQ[bufi]
    auto stage = [&](int step, int bufi) {
        const u16* src = wtH + (step >> 2) * 16384 + (step & 3) * 32;
#pragma unroll
        for (int i = 0; i < 2; ++i) {            // 512 granules, 2/thread
            int u = i * 256 + tid;
            int n = u >> 2, j = u & 3;
            gl_lds16(src + n * 128 + ((j ^ ((n >> 1) & 3)) * 8), &sQ[bufi][u * 8]);
        }
    };
    auto mfma_quarter = [&](int bufi, bf16x8 A) {
        const u16* buf = sQ[bufi];
#pragma unroll
        for (int nt = 0; nt < 8; ++nt) {
            int n = nt * 16 + mm;
            int slot = n * 4 + (qd ^ ((n >> 1) & 3));
            bf16x8 B = *(const bf16x8*)&buf[slot * 8];
            acc[nt] = __builtin_amdgcn_mfma_f32_16x16x32_bf16(A, B, acc[nt], 0, 0, 0);
        }
    };

    // per-relation mean-aggregate, quarter-wave: 4 nodes in flight
    auto gather = [&](int g) {
        int bidx0 = g * NN + row0 + wave * 16;
        int w0 = offs[bidx0];
        int i16 = bidx0 + 16;
        int w1 = (i16 < NRSEG) ? offs[i16] : EE;
        int wcnt = w1 - w0;
        bool fits = (wcnt <= 256);
        if (fits)
            for (int i = lane; i < wcnt; i += 64) sIdx[wb + i] = (int)sorted[w0 + i];

        for (int t2 = 0; t2 < 4; ++t2) {
            int node = t2 * 4 + qd;
            int b = bidx0 + node;
            int r0 = offs[b];
            int r1 = (b + 1 < NRSEG) ? offs[b + 1] : EE;
            int o  = r0 - w0;
            int cnt = r1 - r0;
            float ax[8];
#pragma unroll
            for (int i = 0; i < 8; ++i) ax[i] = 0.f;

            auto upk = [&](uint4 u) {
                ax[0] += __uint_as_float(u.x << 16);
                ax[1] += __uint_as_float(u.x & 0xffff0000u);
                ax[2] += __uint_as_float(u.y << 16);
                ax[3] += __uint_as_float(u.y & 0xffff0000u);
                ax[4] += __uint_as_float(u.z << 16);
                ax[5] += __uint_as_float(u.z & 0xffff0000u);
                ax[6] += __uint_as_float(u.w << 16);
                ax[7] += __uint_as_float(u.w & 0xffff0000u);
            };

            int j = 0;
            if (fits) {
                for (; j + 8 <= cnt; j += 8) {
                    uint4 w0v = *(const uint4*)&hin[sIdx[wb+o+j+0] * DD + mm * 8];
                    uint4 w1v = *(const uint4*)&hin[sIdx[wb+o+j+1] * DD + mm * 8];
                    uint4 w2v = *(const uint4*)&hin[sIdx[wb+o+j+2] * DD + mm * 8];
                    uint4 w3v = *(const uint4*)&hin[sIdx[wb+o+j+3] * DD + mm * 8];
                    uint4 w4v = *(const uint4*)&hin[sIdx[wb+o+j+4] * DD + mm * 8];
                    uint4 w5v = *(const uint4*)&hin[sIdx[wb+o+j+5] * DD + mm * 8];
                    uint4 w6v = *(const uint4*)&hin[sIdx[wb+o+j+6] * DD + mm * 8];
                    uint4 w7v = *(const uint4*)&hin[sIdx[wb+o+j+7] * DD + mm * 8];
                    upk(w0v); upk(w1v); upk(w2v); upk(w3v);
                    upk(w4v); upk(w5v); upk(w6v); upk(w7v);
                }
                for (; j < cnt; ++j)
                    upk(*(const uint4*)&hin[sIdx[wb+o+j] * DD + mm * 8]);
            } else {
                for (; j + 4 <= cnt; j += 4) {
                    uint4 w0v = *(const uint4*)&hin[(int)sorted[r0+j+0] * DD + mm * 8];
                    uint4 w1v = *(const uint4*)&hin[(int)sorted[r0+j+1] * DD + mm * 8];
                    uint4 w2v = *(const uint4*)&hin[(int)sorted[r0+j+2] * DD + mm * 8];
                    uint4 w3v = *(const uint4*)&hin[(int)sorted[r0+j+3] * DD + mm * 8];
                    upk(w0v); upk(w1v); upk(w2v); upk(w3v);
                }
                for (; j < cnt; ++j)
                    upk(*(const uint4*)&hin[(int)sorted[r0+j] * DD + mm * 8]);
            }
            float s = inv[b];
            u32 h0 = bf16_rne(ax[0] * s), h1 = bf16_rne(ax[1] * s);
            u32 h2 = bf16_rne(ax[2] * s), h3 = bf16_rne(ax[3] * s);
            u32 h4 = bf16_rne(ax[4] * s), h5 = bf16_rne(ax[5] * s);
            u32 h6 = bf16_rne(ax[6] * s), h7 = bf16_rne(ax[7] * s);
            uint4 pk;
            pk.x = h0 | (h1 << 16); pk.y = h2 | (h3 << 16);
            pk.z = h4 | (h5 << 16); pk.w = h6 | (h7 << 16);
            writeFragQ(node, pk);
        }
    };

    // ---- prologue: stage (mat0,q0); root A-frags from hin (already bf16) ----
    stage(0, 0);
#pragma unroll
    for (int t2 = 0; t2 < 4; ++t2) {
        int node = t2 * 4 + qd;
        uint4 u = *(const uint4*)&hin[(row0 + wave * 16 + node) * DD + mm * 8];
        writeFragQ(node, u);
    }
    __syncthreads();                             // buf0 DMA drained

    // ---- 5 matrices: mat0 = root, mat 1..4 = rel 0..3 ----
    for (int m = 0; m < 5; ++m) {
        bf16x8 AH[4];
        loadA(AH);
#pragma unroll
        for (int q = 0; q < 4; ++q) {
            int step = m * 4 + q;
            if (step + 1 < 20) stage(step + 1, (step + 1) & 1);
            mfma_quarter(step & 1, AH[q]);
            __syncthreads();                     // next buf drained; this buf free
        }
        if (m < 4) gather(m);                    // refill fH (wave-private; AH dead)
    }

    // ---- epilogue ----
    float bvv[8];
#pragma unroll
    for (int nt = 0; nt < 8; ++nt) bvv[nt] = bias[nt * 16 + mm];

    if constexpr (LAST) {
        int gidx = row0 >> 7;                    // 64-node blocks never straddle graphs
#pragma unroll
        for (int nt = 0; nt < 8; ++nt) {
            float v0 = acc[nt][0], v1 = acc[nt][1], v2 = acc[nt][2], v3 = acc[nt][3];
            float v = fmaxf(fmaxf(v0, v1), fmaxf(v2, v3)) + bvv[nt];
            v = fmaxf(v, 0.f);                   // relu(max) == max(relu) per column
            v = fmaxf(v, __shfl_xor(v, 16));
            v = fmaxf(v, __shfl_xor(v, 32));
            if (lane < 16)
                atomicMax((u32*)&outF[gidx * DD + nt * 16 + mm], __float_as_uint(v));
        }
    } else {
        u16* fs = &fH[wbU];                      // bounce for coalesced bf16 rows
#pragma unroll
        for (int nt = 0; nt < 8; ++nt)
#pragma unroll
            for (int r = 0; r < 4; ++r)
                fs[(qd * 4 + r) * 128 + nt * 16 + mm] =
                    (u16)bf16_rne(fmaxf(acc[nt][r] + bvv[nt], 0.f));
        uint4* dst = (uint4*)&houtH[(row0 + wave * 16) * DD];
        const uint4* src = (const uint4*)fs;
#pragma unroll
        for (int i = 0; i < 4; ++i) dst[i * 64 + lane] = src[i * 64 + lane];
    }
}

// ---------------- launch ----------------

extern "C" void kernel_launch(void* const* d_in, const int* in_sizes, int n_in,
                              void* d_out, int out_size, void* d_ws, size_t ws_size,
                              hipStream_t stream) {
    const float* x      = (const float*)d_in[0];
    const int*   ei     = (const int*)  d_in[1];
    const int*   ea     = (const int*)  d_in[2];
    const float* W_emb  = (const float*)d_in[3];
    const float* b_emb  = (const float*)d_in[4];
    const float* W_root = (const float*)d_in[5];
    const float* W_rel  = (const float*)d_in[6];
    const float* bias   = (const float*)d_in[7];
    float* out = (float*)d_out;

    char* p = (char*)d_ws;
    u16*      h0H    = (u16*)p;      p += (size_t)NN * DD * 2;      // 16.78 MB
    u16*      h1H    = (u16*)p;      p += (size_t)NN * DD * 2;      // 16.78 MB
    int*      hist   = (int*)p;      p += (size_t)NRSEG * 4;        // 1 MB
    u32*      ticket = (u32*)p;                                     // | zeroed with
    u64*      stat   = (u64*)(p + 8); p += 4096;                    // | hist (4 KB)
    float*    inv    = (float*)p;    p += (size_t)NRSEG * 4;        // 1 MB
    int*      offs   = (int*)p;      p += (size_t)NRSEG * 4;        // 1 MB
    int*      cursor = (int*)p;      p += (size_t)NRSEG * 4;        // 1 MB
    unsigned* sorted = (unsigned*)p; p += (size_t)EE * 4;           // 6.29 MB
    u16*      wtH    = (u16*)p;      p += (size_t)10 * 16384 * 2;   // 0.33 MB

    hipMemsetAsync(hist, 0, (size_t)NRSEG * 4 + 4096, stream);      // hist+ticket+stat

    k_front  <<<7872, 256, 0, stream>>>(x, W_emb, b_emb, h0H, ei, ea, hist,
                                        W_root, W_rel, wtH, out);
    k_scan   <<<256, 256, 0, stream>>>(hist, offs, cursor, inv, ticket, stat);
    k_scatter<<<EE / 256, 256, 0, stream>>>(ei, ea, cursor, sorted);

    k_layer<0><<<NN / 64, 256, 0, stream>>>(h0H, h1H, nullptr,
                                            wtH, bias, sorted, offs, inv);
    k_layer<1><<<NN / 64, 256, 0, stream>>>(h1H, nullptr, out,
                                            wtH + 81920, bias + 128,
                                            sorted, offs, inv);
}

// Round 9
// 353.939 us; speedup vs baseline: 2.0764x; 1.1845x over previous
//
#include <hip/hip_runtime.h>

// Problem constants
constexpr int GG    = 512;          // graphs
constexpr int NPG   = 128;          // nodes per graph
constexpr int FIN   = 64;
constexpr int DD    = 128;
constexpr int RR    = 4;
constexpr int NN    = GG * NPG;     // 65536 nodes
constexpr int EE    = 1572864;      // edges
constexpr int NRSEG = NN * RR;      // 262144 segments (key = r*NN + dst)
constexpr int BCAP  = 7680;         // per-bucket capacity in k_binB (avg 6144, sd ~78)

typedef __attribute__((ext_vector_type(8))) short bf16x8;
typedef __attribute__((ext_vector_type(4))) float f32x4;
typedef unsigned short u16;
typedef unsigned int   u32;
typedef unsigned long long u64;

__device__ __forceinline__ u32 bf16_rne(float x) {
    u32 u = __float_as_uint(x);
    return (u + 0x7FFFu + ((u >> 16) & 1u)) >> 16;
}

// async global->LDS DMA, 16 B per lane; LDS side must be uniform-base + lane*16
__device__ __forceinline__ void gl_lds16(const void* g, void* l) {
    __builtin_amdgcn_global_load_lds((const __attribute__((address_space(1))) u32*)g,
                                     (__attribute__((address_space(3))) u32*)l, 16, 0, 0);
}

// ---------------- fused front: prep + embed + hist + out-zero ----------------
// blocks [0,1024): embed | [1024,7168): hist | [7168,7808): prep | [7808,7872): zero out
// NOTE: zero-out covers ALL GG*DD floats (float4/thread) — harness re-poisons
// d_out to 0xAA each replay; uint-punned atomicMax would keep poison otherwise.

__global__ __launch_bounds__(256, 2) void k_front(const float* __restrict__ x,
                                                  const float* __restrict__ W_emb,
                                                  const float* __restrict__ b_emb,
                                                  u16* __restrict__ h,
                                                  const int* __restrict__ ei,
                                                  const int* __restrict__ ea,
                                                  int* __restrict__ hist,
                                                  const float* __restrict__ W_root,
                                                  const float* __restrict__ W_rel,
                                                  u16* __restrict__ wtH,
                                                  float* __restrict__ outF) {
    __shared__ float sA[16 * 64];
    __shared__ float sB[16 * 128];
    int tid = threadIdx.x;
    int bid = blockIdx.x;

    if (bid < 1024) {
        // ---- embed: h = bf16(x @ W_emb + b_emb) ----
        int tx = tid & 31, ty = tid >> 5;
        int row0 = bid * 64;
        float4 bv = *(const float4*)&b_emb[tx * 4];
        float acc[8][4];
#pragma unroll
        for (int i = 0; i < 8; ++i) { acc[i][0]=bv.x; acc[i][1]=bv.y; acc[i][2]=bv.z; acc[i][3]=bv.w; }
        for (int kb = 0; kb < 4; ++kb) {
            {
                int rr = tid >> 2, kq = tid & 3;
                float4 v = *(const float4*)&x[(row0 + rr) * FIN + kb * 16 + kq * 4];
                sA[(kq*4+0)*64 + rr] = v.x;
                sA[(kq*4+1)*64 + rr] = v.y;
                sA[(kq*4+2)*64 + rr] = v.z;
                sA[(kq*4+3)*64 + rr] = v.w;
            }
#pragma unroll
            for (int i = 0; i < 2; ++i) {
                int f = tid + i * 256;
                *(float4*)&sB[f * 4] = *(const float4*)&W_emb[kb * 16 * 128 + f * 4];
            }
            __syncthreads();
#pragma unroll
            for (int kk = 0; kk < 16; ++kk) {
                float4 a0 = *(const float4*)&sA[kk * 64 + ty * 4];
                float4 a1 = *(const float4*)&sA[kk * 64 + 32 + ty * 4];
                float4 bq = *(const float4*)&sB[kk * 128 + tx * 4];
                float ar[8] = {a0.x,a0.y,a0.z,a0.w,a1.x,a1.y,a1.z,a1.w};
#pragma unroll
                for (int i = 0; i < 8; ++i) {
                    acc[i][0] = fmaf(ar[i], bq.x, acc[i][0]);
                    acc[i][1] = fmaf(ar[i], bq.y, acc[i][1]);
                    acc[i][2] = fmaf(ar[i], bq.z, acc[i][2]);
                    acc[i][3] = fmaf(ar[i], bq.w, acc[i][3]);
                }
            }
            __syncthreads();
        }
#pragma unroll
        for (int i = 0; i < 8; ++i) {
            int row = (i < 4) ? (ty * 4 + i) : (32 + ty * 4 + (i - 4));
            u32 s0 = bf16_rne(acc[i][0]), s1 = bf16_rne(acc[i][1]);
            u32 s2 = bf16_rne(acc[i][2]), s3 = bf16_rne(acc[i][3]);
            *(uint2*)&h[(row0 + row) * DD + tx * 4] = make_uint2(s0 | (s1 << 16), s2 | (s3 << 16));
        }
    } else if (bid < 7168) {
        // ---- hist ----
        int e = (bid - 1024) * 256 + tid;      // covers EE exactly
        int dst = ei[EE + e];
        int a   = ea[e];
        atomicAdd(&hist[a * NN + dst], 1);
    } else if (bid < 7808) {
        // ---- prep: transpose weights to bf16, wt[mat*16384 + n*128 + k] ----
        int idx = (bid - 7168) * 256 + tid;    // covers 10*16384
        int mat = idx >> 14;
        int rem = idx & 16383;
        int n = rem >> 7, k = rem & 127;
        int l = mat / 5, m5 = mat - l * 5;
        float v = (m5 == 0) ? W_root[l * 16384 + k * 128 + n]
                            : W_rel[((l * RR + (m5 - 1)) * 128 + k) * 128 + n];
        wtH[idx] = (u16)bf16_rne(v);
    } else {
        // ---- zero out (fused maxpool init; relu >= 0): float4 covers GG*DD ----
        int i = (bid - 7808) * 256 + tid;      // 16384 threads x 4 floats = 65536
        *(float4*)&outF[i * 4] = make_float4(0.f, 0.f, 0.f, 0.f);
    }
}

// ---------------- single-pass scan (decoupled lookback, 256 tiles) -----------
// Tile t covers keys [t*1024,(t+1)*1024) == bucket t; publishes bucket start
// into bcur for k_binA's run reservation. Ticket order = acquire order.

__global__ __launch_bounds__(256) void k_scan(const int* __restrict__ hist,
                                              int* __restrict__ offs,
                                              int* __restrict__ cursor,
                                              float* __restrict__ inv,
                                              u32* __restrict__ ticket,
                                              u64* __restrict__ stat,
                                              u32* __restrict__ bcur) {
    __shared__ int ts[256];
    __shared__ int sh[2];
    int tid = threadIdx.x;
    if (tid == 0) sh[0] = (int)atomicAdd(ticket, 1u);
    __syncthreads();
    int tile = sh[0];

    int base = tile * 1024 + tid * 4;
    int4 v = *(const int4*)(hist + base);
    float4 iv;
    iv.x = 1.0f / (float)(v.x > 0 ? v.x : 1);
    iv.y = 1.0f / (float)(v.y > 0 ? v.y : 1);
    iv.z = 1.0f / (float)(v.z > 0 ? v.z : 1);
    iv.w = 1.0f / (float)(v.w > 0 ? v.w : 1);
    *(float4*)&inv[base] = iv;

    int s = v.x + v.y + v.z + v.w;
    ts[tid] = s;
    __syncthreads();
    for (int ofs = 1; ofs < 256; ofs <<= 1) {
        int t = (tid >= ofs) ? ts[tid - ofs] : 0;
        __syncthreads();
        ts[tid] += t;
        __syncthreads();
    }
    int total = ts[255];

    if (tid == 0)                              // publish partial before any wait
        atomicExch(&stat[tile], (1ull << 62) | (u64)(u32)total);

    if (tid < 64) {                            // wave-parallel lookback
        int lane = tid;
        int ex = 0;
        int t = tile - 1;
        while (t >= 0) {
            int idx = t - lane;
            int st; u32 val;
            if (idx >= 0) {
                u64 w;
                do {
                    w = atomicAdd(&stat[idx], 0ull);
                    st = (int)(w >> 62);
                    if (!st) __builtin_amdgcn_s_sleep(1);
                } while (!st);
                val = (u32)(w & 0xFFFFFFFFull);
            } else { st = 2; val = 0; }        // virtual prefix-0 below tile 0
            u64 ball = __ballot(st == 2);
            int p = (ball != 0) ? (__ffsll((long long)ball) - 1) : -1;
            int contrib = (p < 0 || lane <= p) ? (int)val : 0;
#pragma unroll
            for (int o = 32; o > 0; o >>= 1) contrib += __shfl_down(contrib, o);
            contrib = __shfl(contrib, 0);
            ex += contrib;
            if (p >= 0) break;
            t -= 64;
        }
        if (lane == 0) {
            sh[1] = ex;
            atomicExch(&stat[tile], (2ull << 62) | (u64)(u32)(ex + total));
        }
    }
    __syncthreads();

    int b0 = sh[1];
    if (tid == 0) bcur[tile] = (u32)b0;        // bucket start for k_binA
    int excl = ts[tid] - s + b0;
    int4 o4;
    o4.x = excl;
    o4.y = excl + v.x;
    o4.z = excl + v.x + v.y;
    o4.w = excl + v.x + v.y + v.z;
    *(int4*)&offs[base]   = o4;
    *(int4*)&cursor[base] = o4;
}

// ---------------- bucketed scatter phase A: bin edges by bucket --------------
// bucket = key>>10 = (a<<6)|(dst>>10). Block owns 8192 edges; LDS histogram,
// one global atomic per (block,bucket) reserves a contiguous run in binned;
// writes are 256 runs x ~128 B per block -> line-local (vs 4 B random).

__global__ __launch_bounds__(256) void k_binA(const int* __restrict__ ei,
                                              const int* __restrict__ ea,
                                              u32* __restrict__ bcur,
                                              u32* __restrict__ binned) {
    __shared__ int bh[256];
    __shared__ int lcur[256];
    int tid = threadIdx.x;
    int e0 = blockIdx.x * 8192;                // 192 blocks cover EE exactly
    bh[tid] = 0;
    __syncthreads();
    for (int i = 0; i < 32; ++i) {
        int e = e0 + i * 256 + tid;
        int dst = ei[EE + e];
        int a   = ea[e];
        atomicAdd(&bh[(a << 6) | (dst >> 10)], 1);
    }
    __syncthreads();
    lcur[tid] = (int)atomicAdd(&bcur[tid], (u32)bh[tid]);
    __syncthreads();
    for (int i = 0; i < 32; ++i) {
        int e = e0 + i * 256 + tid;
        int src = ei[e];
        int dst = ei[EE + e];
        int a   = ea[e];
        int pos = atomicAdd(&lcur[(a << 6) | (dst >> 10)], 1);
        binned[pos] = (u32)src | ((u32)dst << 16);
    }
}

// ---------------- bucketed scatter phase B: within-bucket sort ---------------
// One block per bucket (contiguous [p0,p1) in the final array). Subkey =
// dst&1023 (1024 keys/bucket). LDS count + prefix + rank -> LDS staging ->
// contiguous flush of u16 srcs. Fallback: global cursor scatter (never in
// practice; bucket sizes ~6144 +- 80).

__global__ __launch_bounds__(256) void k_binB(const u32* __restrict__ binned,
                                              const int* __restrict__ offs,
                                              int* __restrict__ cursor,
                                              u16* __restrict__ sorted) {
    __shared__ int pc[1024];
    __shared__ int ts[256];
    __shared__ u16 stg[BCAP];
    int tid = threadIdx.x;
    int b = blockIdx.x;
    int p0 = offs[b << 10];
    int p1 = (b == 255) ? EE : offs[(b + 1) << 10];
    int cnt = p1 - p0;

    if (cnt <= BCAP) {
#pragma unroll
        for (int i = 0; i < 4; ++i) pc[i * 256 + tid] = 0;
        __syncthreads();
        for (int i = tid; i < cnt; i += 256) {
            u32 rec = binned[p0 + i];
            atomicAdd(&pc[(rec >> 16) & 1023], 1);
        }
        __syncthreads();
        int v[4], s = 0;
#pragma unroll
        for (int i = 0; i < 4; ++i) { v[i] = pc[tid * 4 + i]; s += v[i]; }
        ts[tid] = s;
        __syncthreads();
        for (int o = 1; o < 256; o <<= 1) {
            int t = (tid >= o) ? ts[tid - o] : 0;
            __syncthreads();
            ts[tid] += t;
            __syncthreads();
        }
        int ex = ts[tid] - s;
#pragma unroll
        for (int i = 0; i < 4; ++i) { pc[tid * 4 + i] = ex; ex += v[i]; }
        __syncthreads();
        for (int i = tid; i < cnt; i += 256) {
            u32 rec = binned[p0 + i];
            int pos = atomicAdd(&pc[(rec >> 16) & 1023], 1);
            stg[pos] = (u16)(rec & 0xFFFFu);
        }
        __syncthreads();
        for (int i = tid; i < cnt; i += 256) sorted[p0 + i] = stg[i];
    } else {
        for (int i = tid; i < cnt; i += 256) {
            u32 rec = binned[p0 + i];
            int dst = (int)(rec >> 16);
            int key = (b >> 6) * NN + dst;
            int pos = atomicAdd(&cursor[key], 1);
            sorted[pos] = (u16)(rec & 0xFFFFu);
        }
    }
}

// ---------------- fused RGCN layer ----------------
// 256 threads = 4 waves; wave owns a 16-node M-strip.
// Gather: quarter-wave (16 lanes/node, uint4 16B/lane, 4 chains in flight).
// B staged in k-quarters (8 KB), double-buffered, XOR-swizzled (conflict-free).
// LDS: fH 16K + sQ 16K + sIdx 4K = 36864 B -> 4 blocks/CU.

template<int LAST>
__global__ __launch_bounds__(256, 4) void k_layer(const u16* __restrict__ hin,
                                                  u16* __restrict__ houtH,
                                                  float* __restrict__ outF,
                                                  const u16* __restrict__ wtH,
                                                  const float* __restrict__ bias,
                                                  const u16* __restrict__ sorted,
                                                  const int* __restrict__ offs,
                                                  const float* __restrict__ inv) {
    __shared__ __align__(16) u16 fH[4 * 2048];   // 16 KB A-frags (swizzled, wave-private)
    __shared__ __align__(16) u16 sQ[2][4096];    // 2 x 8 KB B k-quarter buffers
    __shared__ int sIdx[4 * 256];                // 4 KB gather index scratch

    int tid  = threadIdx.x;
    int wave = tid >> 6, lane = tid & 63;
    int mm   = lane & 15;            // MFMA m/n lane; gather col-octet
    int qd   = lane >> 4;            // MFMA quad; gather quarter (node group)
    int row0 = blockIdx.x * 64;
    int wbU  = wave * 2048;          // fH wave base (u16)
    int wb   = wave * 256;           // sIdx wave base (ints)

    f32x4 acc[8];
#pragma unroll
    for (int i = 0; i < 8; ++i) acc[i] = (f32x4){0.f, 0.f, 0.f, 0.f};

    // granule slot for A-frag: f(node, ks, g) = ks*64 + g*16 + (node ^ (ks*4+g))
    auto writeFragQ = [&](int node, uint4 u) {   // lane's cols = mm*8..+7
        int ks = mm >> 2, g = mm & 3;
        int slot = ks * 64 + g * 16 + (node ^ (ks * 4 + g));
        *(uint4*)&fH[wbU + slot * 8] = u;
    };
    auto loadA = [&](bf16x8* AH) {
#pragma unroll
        for (int ks = 0; ks < 4; ++ks) {
            int slot = ks * 64 + qd * 16 + (mm ^ (ks * 4 + qd));
            AH[ks] = *(const bf16x8*)&fH[wbU + slot * 8];
        }
    };

    // stage k-quarter `step` (mat step>>2, cols (step&3)*32..) into sQ[bufi]
    auto stage = [&](int step, int bufi) {
        const u16* src = wtH + (step >> 2) * 16384 + (step & 3) * 32;
#pragma unroll
        for (int i = 0; i < 2; ++i) {            // 512 granules, 2/thread
            int u = i * 256 + tid;
            int n = u >> 2, j = u & 3;
            gl_lds16(src + n * 128 + ((j ^ ((n >> 1) & 3)) * 8), &sQ[bufi][u * 8]);
        }
    };
    auto mfma_quarter = [&](int bufi, bf16x8 A) {
        const u16* buf = sQ[bufi];
#pragma unroll
        for (int nt = 0; nt < 8; ++nt) {
            int n = nt * 16 + mm;
            int slot = n * 4 + (qd ^ ((n >> 1) & 3));
            bf16x8 B = *(const bf16x8*)&buf[slot * 8];
            acc[nt] = __builtin_amdgcn_mfma_f32_16x16x32_bf16(A, B, acc[nt], 0, 0, 0);
        }
    };

    // per-relation mean-aggregate, quarter-wave: 4 nodes in flight
    auto gather = [&](int g) {
        int bidx0 = g * NN + row0 + wave * 16;
        int w0 = offs[bidx0];
        int i16 = bidx0 + 16;
        int w1 = (i16 < NRSEG) ? offs[i16] : EE;
        int wcnt = w1 - w0;
        bool fits = (wcnt <= 256);
        if (fits)
            for (int i = lane; i < wcnt; i += 64) sIdx[wb + i] = (int)sorted[w0 + i];

        for (int t2 = 0; t2 < 4; ++t2) {
            int node = t2 * 4 + qd;
            int b = bidx0 + node;
            int r0 = offs[b];
            int r1 = (b + 1 < NRSEG) ? offs[b + 1] : EE;
            int o  = r0 - w0;
            int cnt = r1 - r0;
            float ax[8];
#pragma unroll
            for (int i = 0; i < 8; ++i) ax[i] = 0.f;

            auto upk = [&](uint4 u) {
                ax[0] += __uint_as_float(u.x << 16);
                ax[1] += __uint_as_float(u.x & 0xffff0000u);
                ax[2] += __uint_as_float(u.y << 16);
                ax[3] += __uint_as_float(u.y & 0xffff0000u);
                ax[4] += __uint_as_float(u.z << 16);
                ax[5] += __uint_as_float(u.z & 0xffff0000u);
                ax[6] += __uint_as_float(u.w << 16);
                ax[7] += __uint_as_float(u.w & 0xffff0000u);
            };

            int j = 0;
            if (fits) {
                for (; j + 8 <= cnt; j += 8) {
                    uint4 w0v = *(const uint4*)&hin[sIdx[wb+o+j+0] * DD + mm * 8];
                    uint4 w1v = *(const uint4*)&hin[sIdx[wb+o+j+1] * DD + mm * 8];
                    uint4 w2v = *(const uint4*)&hin[sIdx[wb+o+j+2] * DD + mm * 8];
                    uint4 w3v = *(const uint4*)&hin[sIdx[wb+o+j+3] * DD + mm * 8];
                    uint4 w4v = *(const uint4*)&hin[sIdx[wb+o+j+4] * DD + mm * 8];
                    uint4 w5v = *(const uint4*)&hin[sIdx[wb+o+j+5] * DD + mm * 8];
                    uint4 w6v = *(const uint4*)&hin[sIdx[wb+o+j+6] * DD + mm * 8];
                    uint4 w7v = *(const uint4*)&hin[sIdx[wb+o+j+7] * DD + mm * 8];
                    upk(w0v); upk(w1v); upk(w2v); upk(w3v);
                    upk(w4v); upk(w5v); upk(w6v); upk(w7v);
                }
                for (; j < cnt; ++j)
                    upk(*(const uint4*)&hin[sIdx[wb+o+j] * DD + mm * 8]);
            } else {
                for (; j + 4 <= cnt; j += 4) {
                    uint4 w0v = *(const uint4*)&hin[(int)sorted[r0+j+0] * DD + mm * 8];
                    uint4 w1v = *(const uint4*)&hin[(int)sorted[r0+j+1] * DD + mm * 8];
                    uint4 w2v = *(const uint4*)&hin[(int)sorted[r0+j+2] * DD + mm * 8];
                    uint4 w3v = *(const uint4*)&hin[(int)sorted[r0+j+3] * DD + mm * 8];
                    upk(w0v); upk(w1v); upk(w2v); upk(w3v);
                }
                for (; j < cnt; ++j)
                    upk(*(const uint4*)&hin[(int)sorted[r0+j] * DD + mm * 8]);
            }
            float s = inv[b];
            u32 h0 = bf16_rne(ax[0] * s), h1 = bf16_rne(ax[1] * s);
            u32 h2 = bf16_rne(ax[2] * s), h3 = bf16_rne(ax[3] * s);
            u32 h4 = bf16_rne(ax[4] * s), h5 = bf16_rne(ax[5] * s);
            u32 h6 = bf16_rne(ax[6] * s), h7 = bf16_rne(ax[7] * s);
            uint4 pk;
            pk.x = h0 | (h1 << 16); pk.y = h2 | (h3 << 16);
            pk.z = h4 | (h5 << 16); pk.w = h6 | (h7 << 16);
            writeFragQ(node, pk);
        }
    };

    // ---- prologue: stage (mat0,q0); root A-frags from hin (already bf16) ----
    stage(0, 0);
#pragma unroll
    for (int t2 = 0; t2 < 4; ++t2) {
        int node = t2 * 4 + qd;
        uint4 u = *(const uint4*)&hin[(row0 + wave * 16 + node) * DD + mm * 8];
        writeFragQ(node, u);
    }
    __syncthreads();                             // buf0 DMA drained

    // ---- 5 matrices: mat0 = root, mat 1..4 = rel 0..3 ----
    for (int m = 0; m < 5; ++m) {
        bf16x8 AH[4];
        loadA(AH);
#pragma unroll
        for (int q = 0; q < 4; ++q) {
            int step = m * 4 + q;
            if (step + 1 < 20) stage(step + 1, (step + 1) & 1);
            mfma_quarter(step & 1, AH[q]);
            __syncthreads();                     // next buf drained; this buf free
        }
        if (m < 4) gather(m);                    // refill fH (wave-private; AH dead)
    }

    // ---- epilogue ----
    float bvv[8];
#pragma unroll
    for (int nt = 0; nt < 8; ++nt) bvv[nt] = bias[nt * 16 + mm];

    if constexpr (LAST) {
        int gidx = row0 >> 7;                    // 64-node blocks never straddle graphs
#pragma unroll
        for (int nt = 0; nt < 8; ++nt) {
            float v0 = acc[nt][0], v1 = acc[nt][1], v2 = acc[nt][2], v3 = acc[nt][3];
            float v = fmaxf(fmaxf(v0, v1), fmaxf(v2, v3)) + bvv[nt];
            v = fmaxf(v, 0.f);                   // relu(max) == max(relu) per column
            v = fmaxf(v, __shfl_xor(v, 16));
            v = fmaxf(v, __shfl_xor(v, 32));
            if (lane < 16)
                atomicMax((u32*)&outF[gidx * DD + nt * 16 + mm], __float_as_uint(v));
        }
    } else {
        u16* fs = &fH[wbU];                      // bounce for coalesced bf16 rows
#pragma unroll
        for (int nt = 0; nt < 8; ++nt)
#pragma unroll
            for (int r = 0; r < 4; ++r)
                fs[(qd * 4 + r) * 128 + nt * 16 + mm] =
                    (u16)bf16_rne(fmaxf(acc[nt][r] + bvv[nt], 0.f));
        uint4* dst = (uint4*)&houtH[(row0 + wave * 16) * DD];
        const uint4* src = (const uint4*)fs;
#pragma unroll
        for (int i = 0; i < 4; ++i) dst[i * 64 + lane] = src[i * 64 + lane];
    }
}

// ---------------- launch ----------------

extern "C" void kernel_launch(void* const* d_in, const int* in_sizes, int n_in,
                              void* d_out, int out_size, void* d_ws, size_t ws_size,
                              hipStream_t stream) {
    const float* x      = (const float*)d_in[0];
    const int*   ei     = (const int*)  d_in[1];
    const int*   ea     = (const int*)  d_in[2];
    const float* W_emb  = (const float*)d_in[3];
    const float* b_emb  = (const float*)d_in[4];
    const float* W_root = (const float*)d_in[5];
    const float* W_rel  = (const float*)d_in[6];
    const float* bias   = (const float*)d_in[7];
    float* out = (float*)d_out;

    char* p = (char*)d_ws;
    u16*      h0H    = (u16*)p;      p += (size_t)NN * DD * 2;      // 16.78 MB
    u16*      h1H    = (u16*)p;      p += (size_t)NN * DD * 2;      // 16.78 MB
    int*      hist   = (int*)p;      p += (size_t)NRSEG * 4;        // 1 MB
    u32*      ticket = (u32*)p;                                     // | zeroed with
    u64*      stat   = (u64*)(p + 8); p += 4096;                    // | hist (4 KB)
    float*    inv    = (float*)p;    p += (size_t)NRSEG * 4;        // 1 MB
    int*      offs   = (int*)p;      p += (size_t)NRSEG * 4;        // 1 MB
    int*      cursor = (int*)p;      p += (size_t)NRSEG * 4;        // 1 MB
    u32*      bcur   = (u32*)p;      p += 1024;                     // 256 bucket cursors
    u32*      binned = (u32*)p;      p += (size_t)EE * 4;           // 6.29 MB
    u16*      sorted = (u16*)p;      p += (size_t)EE * 2;           // 3.15 MB
    u16*      wtH    = (u16*)p;      p += (size_t)10 * 16384 * 2;   // 0.33 MB

    hipMemsetAsync(hist, 0, (size_t)NRSEG * 4 + 4096, stream);      // hist+ticket+stat

    k_front<<<7872, 256, 0, stream>>>(x, W_emb, b_emb, h0H, ei, ea, hist,
                                      W_root, W_rel, wtH, out);
    k_scan <<<256, 256, 0, stream>>>(hist, offs, cursor, inv, ticket, stat, bcur);
    k_binA <<<192, 256, 0, stream>>>(ei, ea, bcur, binned);
    k_binB <<<256, 256, 0, stream>>>(binned, offs, cursor, sorted);

    k_layer<0><<<NN / 64, 256, 0, stream>>>(h0H, h1H, nullptr,
                                            wtH, bias, sorted, offs, inv);
    k_layer<1><<<NN / 64, 256, 0, stream>>>(h1H, nullptr, out,
                                            wtH + 81920, bias + 128,
                                            sorted, offs, inv);
}

// Round 10
// 286.099 us; speedup vs baseline: 2.5688x; 1.2371x over previous
//
#include <hip/hip_runtime.h>

// Problem constants
constexpr int GG    = 512;          // graphs
constexpr int NPG   = 128;          // nodes per graph
constexpr int FIN   = 64;
constexpr int DD    = 128;
constexpr int RR    = 4;
constexpr int NN    = GG * NPG;     // 65536 nodes
constexpr int EE    = 1572864;      // edges
constexpr int NRSEG = NN * RR;      // 262144 segments (key = r*NN + dst)
constexpr int BCAP  = 7680;         // per-bucket capacity in k_binB (avg 6144, sd ~78)

typedef __attribute__((ext_vector_type(8))) short bf16x8;
typedef __attribute__((ext_vector_type(4))) float f32x4;
typedef unsigned short u16;
typedef unsigned int   u32;

__device__ __forceinline__ u32 bf16_rne(float x) {
    u32 u = __float_as_uint(x);
    return (u + 0x7FFFu + ((u >> 16) & 1u)) >> 16;
}

// async global->LDS DMA, 16 B per lane; LDS side must be uniform-base + lane*16
__device__ __forceinline__ void gl_lds16(const void* g, void* l) {
    __builtin_amdgcn_global_load_lds((const __attribute__((address_space(1))) u32*)g,
                                     (__attribute__((address_space(3))) u32*)l, 16, 0, 0);
}

// ---------------- fused front: embed + bucket-count + prep + out-zero --------
// blocks [0,1024): embed | [1024,1216): bucket-count | [1216,1856): prep |
// [1856,1920): zero out. NOTE: zero-out covers ALL GG*DD floats — harness
// re-poisons d_out to 0xAA each replay; atomicMax keeps poison otherwise.

__global__ __launch_bounds__(256, 2) void k_front(const float* __restrict__ x,
                                                  const float* __restrict__ W_emb,
                                                  const float* __restrict__ b_emb,
                                                  u16* __restrict__ h,
                                                  const int* __restrict__ ei,
                                                  const int* __restrict__ ea,
                                                  u32* __restrict__ bc,
                                                  const float* __restrict__ W_root,
                                                  const float* __restrict__ W_rel,
                                                  u16* __restrict__ wtH,
                                                  float* __restrict__ outF) {
    __shared__ float sA[16 * 64];
    __shared__ float sB[16 * 128];
    __shared__ int bh[256];
    int tid = threadIdx.x;
    int bid = blockIdx.x;

    if (bid < 1024) {
        // ---- embed: h = bf16(x @ W_emb + b_emb) ----
        int tx = tid & 31, ty = tid >> 5;
        int row0 = bid * 64;
        float4 bv = *(const float4*)&b_emb[tx * 4];
        float acc[8][4];
#pragma unroll
        for (int i = 0; i < 8; ++i) { acc[i][0]=bv.x; acc[i][1]=bv.y; acc[i][2]=bv.z; acc[i][3]=bv.w; }
        for (int kb = 0; kb < 4; ++kb) {
            {
                int rr = tid >> 2, kq = tid & 3;
                float4 v = *(const float4*)&x[(row0 + rr) * FIN + kb * 16 + kq * 4];
                sA[(kq*4+0)*64 + rr] = v.x;
                sA[(kq*4+1)*64 + rr] = v.y;
                sA[(kq*4+2)*64 + rr] = v.z;
                sA[(kq*4+3)*64 + rr] = v.w;
            }
#pragma unroll
            for (int i = 0; i < 2; ++i) {
                int f = tid + i * 256;
                *(float4*)&sB[f * 4] = *(const float4*)&W_emb[kb * 16 * 128 + f * 4];
            }
            __syncthreads();
#pragma unroll
            for (int kk = 0; kk < 16; ++kk) {
                float4 a0 = *(const float4*)&sA[kk * 64 + ty * 4];
                float4 a1 = *(const float4*)&sA[kk * 64 + 32 + ty * 4];
                float4 bq = *(const float4*)&sB[kk * 128 + tx * 4];
                float ar[8] = {a0.x,a0.y,a0.z,a0.w,a1.x,a1.y,a1.z,a1.w};
#pragma unroll
                for (int i = 0; i < 8; ++i) {
                    acc[i][0] = fmaf(ar[i], bq.x, acc[i][0]);
                    acc[i][1] = fmaf(ar[i], bq.y, acc[i][1]);
                    acc[i][2] = fmaf(ar[i], bq.z, acc[i][2]);
                    acc[i][3] = fmaf(ar[i], bq.w, acc[i][3]);
                }
            }
            __syncthreads();
        }
#pragma unroll
        for (int i = 0; i < 8; ++i) {
            int row = (i < 4) ? (ty * 4 + i) : (32 + ty * 4 + (i - 4));
            u32 s0 = bf16_rne(acc[i][0]), s1 = bf16_rne(acc[i][1]);
            u32 s2 = bf16_rne(acc[i][2]), s3 = bf16_rne(acc[i][3]);
            *(uint2*)&h[(row0 + row) * DD + tx * 4] = make_uint2(s0 | (s1 << 16), s2 | (s3 << 16));
        }
    } else if (bid < 1216) {
        // ---- bucket-count: LDS hist of bucket = (a<<6)|(dst>>10) ----
        int e0 = (bid - 1024) * 8192;          // 192 blocks cover EE exactly
        bh[tid] = 0;
        __syncthreads();
        for (int i = 0; i < 32; ++i) {
            int e = e0 + i * 256 + tid;
            int dst = ei[EE + e];
            int a   = ea[e];
            atomicAdd(&bh[(a << 6) | (dst >> 10)], 1);
        }
        __syncthreads();
        atomicAdd(&bc[tid], (u32)bh[tid]);
    } else if (bid < 1856) {
        // ---- prep: transpose weights to bf16, wt[mat*16384 + n*128 + k] ----
        int idx = (bid - 1216) * 256 + tid;    // covers 10*16384
        int mat = idx >> 14;
        int rem = idx & 16383;
        int n = rem >> 7, k = rem & 127;
        int l = mat / 5, m5 = mat - l * 5;
        float v = (m5 == 0) ? W_root[l * 16384 + k * 128 + n]
                            : W_rel[((l * RR + (m5 - 1)) * 128 + k) * 128 + n];
        wtH[idx] = (u16)bf16_rne(v);
    } else {
        // ---- zero out (fused maxpool init; relu >= 0): float4 covers GG*DD ----
        int i = (bid - 1856) * 256 + tid;      // 16384 threads x 4 floats = 65536
        *(float4*)&outF[i * 4] = make_float4(0.f, 0.f, 0.f, 0.f);
    }
}

// ---------------- tiny scan: 256 bucket totals -> bases ----------------------

__global__ __launch_bounds__(256) void k_mini(const u32* __restrict__ bc,
                                              u32* __restrict__ bcur,
                                              u32* __restrict__ bbase) {
    __shared__ int ts[256];
    int tid = threadIdx.x;
    int v = (int)bc[tid];
    ts[tid] = v;
    __syncthreads();
    for (int o = 1; o < 256; o <<= 1) {
        int t = (tid >= o) ? ts[tid - o] : 0;
        __syncthreads();
        ts[tid] += t;
        __syncthreads();
    }
    u32 ex = (u32)(ts[tid] - v);
    bcur[tid]  = ex;
    bbase[tid] = ex;
}

// ---------------- bucketed scatter phase A: bin edges by bucket --------------
// Block owns 8192 edges; LDS histogram, one global atomic per (block,bucket)
// reserves a contiguous run in binned -> line-local writes.

__global__ __launch_bounds__(256) void k_binA(const int* __restrict__ ei,
                                              const int* __restrict__ ea,
                                              u32* __restrict__ bcur,
                                              u32* __restrict__ binned) {
    __shared__ int bh[256];
    __shared__ int lcur[256];
    int tid = threadIdx.x;
    int e0 = blockIdx.x * 8192;                // 192 blocks cover EE exactly
    bh[tid] = 0;
    __syncthreads();
    for (int i = 0; i < 32; ++i) {
        int e = e0 + i * 256 + tid;
        int dst = ei[EE + e];
        int a   = ea[e];
        atomicAdd(&bh[(a << 6) | (dst >> 10)], 1);
    }
    __syncthreads();
    lcur[tid] = (int)atomicAdd(&bcur[tid], (u32)bh[tid]);
    __syncthreads();
    for (int i = 0; i < 32; ++i) {
        int e = e0 + i * 256 + tid;
        int src = ei[e];
        int dst = ei[EE + e];
        int a   = ea[e];
        int pos = atomicAdd(&lcur[(a << 6) | (dst >> 10)], 1);
        binned[pos] = (u32)src | ((u32)dst << 16);
    }
}

// ---------------- bucketed scatter phase B: sort + emit offs/inv -------------
// One block per bucket. Subkey = dst&1023. LDS count + prefix -> writes the
// 1024 segment offsets (offs) and inverse counts (inv) for its key range,
// then rank-scatters srcs (u16) via LDS staging (contiguous flush).

__global__ __launch_bounds__(256) void k_binB(const u32* __restrict__ binned,
                                              const u32* __restrict__ bbase,
                                              int* __restrict__ offs,
                                              float* __restrict__ inv,
                                              u16* __restrict__ sorted) {
    __shared__ int pc[1024];
    __shared__ int ts[256];
    __shared__ u16 stg[BCAP];
    int tid = threadIdx.x;
    int b = blockIdx.x;
    int p0 = (int)bbase[b];
    int p1 = (b == 255) ? EE : (int)bbase[b + 1];
    int cnt = p1 - p0;
    bool fits = (cnt <= BCAP);

#pragma unroll
    for (int i = 0; i < 4; ++i) pc[i * 256 + tid] = 0;
    __syncthreads();
    for (int i = tid; i < cnt; i += 256) {
        u32 rec = binned[p0 + i];
        atomicAdd(&pc[(rec >> 16) & 1023], 1);
    }
    __syncthreads();
    int v[4], s = 0;
#pragma unroll
    for (int i = 0; i < 4; ++i) { v[i] = pc[tid * 4 + i]; s += v[i]; }
    ts[tid] = s;
    __syncthreads();
    for (int o = 1; o < 256; o <<= 1) {
        int t = (tid >= o) ? ts[tid - o] : 0;
        __syncthreads();
        ts[tid] += t;
        __syncthreads();
    }
    int ex = ts[tid] - s;
    // emit offs + inv for this thread's 4 keys, and store local prefix in pc
    {
        int4 o4; float4 i4;
        int e = ex;
#pragma unroll
        for (int i = 0; i < 4; ++i) {
            (&o4.x)[i] = p0 + e;
            (&i4.x)[i] = 1.0f / (float)(v[i] > 0 ? v[i] : 1);
            e += v[i];
        }
        *(int4*)&offs[(b << 10) + tid * 4]  = o4;
        *(float4*)&inv[(b << 10) + tid * 4] = i4;
    }
    __syncthreads();                            // counts consumed
#pragma unroll
    for (int i = 0; i < 4; ++i) { pc[tid * 4 + i] = ex; ex += v[i]; }
    __syncthreads();
    if (fits) {
        for (int i = tid; i < cnt; i += 256) {
            u32 rec = binned[p0 + i];
            int pos = atomicAdd(&pc[(rec >> 16) & 1023], 1);
            stg[pos] = (u16)(rec & 0xFFFFu);
        }
        __syncthreads();
        for (int i = tid; i < cnt; i += 256) sorted[p0 + i] = stg[i];
    } else {
        for (int i = tid; i < cnt; i += 256) {
            u32 rec = binned[p0 + i];
            int pos = atomicAdd(&pc[(rec >> 16) & 1023], 1);
            sorted[p0 + pos] = (u16)(rec & 0xFFFFu);
        }
    }
}

// ---------------- fused RGCN layer ----------------
// 256 threads = 4 waves; wave owns a 16-node M-strip.
// Gather: quarter-wave (16 lanes/node, uint4 16B/lane, 4 chains in flight);
// sIdx double-buffered & prefetched one relation ahead; inv prestaged; offs
// loads hoisted 8-up-front. B staged in k-quarters (8 KB dbuf, XOR-swizzled).
// LDS: fH 16K + sQ 16K + sIdx 6K + sInv 1K + sMeta = 40000 B -> 4 blocks/CU.

constexpr int ICAP = 192;   // per-wave sIdx capacity (wcnt avg 96, sd ~10)

template<int LAST>
__global__ __launch_bounds__(256, 4) void k_layer(const u16* __restrict__ hin,
                                                  u16* __restrict__ houtH,
                                                  float* __restrict__ outF,
                                                  const u16* __restrict__ wtH,
                                                  const float* __restrict__ bias,
                                                  const u16* __restrict__ sorted,
                                                  const int* __restrict__ offs,
                                                  const float* __restrict__ inv) {
    __shared__ __align__(16) u16 fH[4 * 2048];   // 16 KB A-frags (swizzled, wave-private)
    __shared__ __align__(16) u16 sQ[2][4096];    // 2 x 8 KB B k-quarter buffers
    __shared__ int   sIdx[2][4 * ICAP];          // 6 KB dbuf gather indices
    __shared__ float sInv[4 * 64];               // 1 KB prestaged inverse counts
    __shared__ int   sMeta[2][4][2];             // (w0, w1) per buf/wave

    int tid  = threadIdx.x;
    int wave = tid >> 6, lane = tid & 63;
    int mm   = lane & 15;            // MFMA m/n lane; gather col-octet
    int qd   = lane >> 4;            // MFMA quad; gather quarter (node group)
    int row0 = blockIdx.x * 64;
    int wbU  = wave * 2048;          // fH wave base (u16)

    f32x4 acc[8];
#pragma unroll
    for (int i = 0; i < 8; ++i) acc[i] = (f32x4){0.f, 0.f, 0.f, 0.f};

    // granule slot for A-frag: f(node, ks, g) = ks*64 + g*16 + (node ^ (ks*4+g))
    auto writeFragQ = [&](int node, uint4 u) {   // lane's cols = mm*8..+7
        int ks = mm >> 2, g = mm & 3;
        int slot = ks * 64 + g * 16 + (node ^ (ks * 4 + g));
        *(uint4*)&fH[wbU + slot * 8] = u;
    };
    auto loadA = [&](bf16x8* AH) {
#pragma unroll
        for (int ks = 0; ks < 4; ++ks) {
            int slot = ks * 64 + qd * 16 + (mm ^ (ks * 4 + qd));
            AH[ks] = *(const bf16x8*)&fH[wbU + slot * 8];
        }
    };

    // stage k-quarter `step` (mat step>>2, cols (step&3)*32..) into sQ[bufi]
    auto stage = [&](int step, int bufi) {
        const u16* src = wtH + (step >> 2) * 16384 + (step & 3) * 32;
#pragma unroll
        for (int i = 0; i < 2; ++i) {            // 512 granules, 2/thread
            int u = i * 256 + tid;
            int n = u >> 2, j = u & 3;
            gl_lds16(src + n * 128 + ((j ^ ((n >> 1) & 3)) * 8), &sQ[bufi][u * 8]);
        }
    };
    auto mfma_quarter = [&](int bufi, bf16x8 A) {
        const u16* buf = sQ[bufi];
#pragma unroll
        for (int nt = 0; nt < 8; ++nt) {
            int n = nt * 16 + mm;
            int slot = n * 4 + (qd ^ ((n >> 1) & 3));
            bf16x8 B = *(const bf16x8*)&buf[slot * 8];
            acc[nt] = __builtin_amdgcn_mfma_f32_16x16x32_bf16(A, B, acc[nt], 0, 0, 0);
        }
    };

    // prefetch relation g's sorted-index range into sIdx[sbuf] (wave-private)
    auto prefetchIdx = [&](int g, int sbuf) {
        int bidx0 = g * NN + row0 + wave * 16;
        int w0 = offs[bidx0];
        int i16 = bidx0 + 16;
        int w1 = (i16 < NRSEG) ? offs[i16] : EE;
        if (lane == 0) { sMeta[sbuf][wave][0] = w0; sMeta[sbuf][wave][1] = w1; }
        int wcnt = w1 - w0;
        if (wcnt > ICAP) wcnt = ICAP;            // fallback handled in gather
        for (int i = lane; i < wcnt; i += 64)
            sIdx[sbuf][wave * ICAP + i] = (int)sorted[w0 + i];
    };

    // per-relation mean-aggregate, quarter-wave: 4 nodes in flight
    auto gather = [&](int g, int sbuf) {
        int bidx0 = g * NN + row0 + wave * 16;
        int w0 = sMeta[sbuf][wave][0];
        int w1 = sMeta[sbuf][wave][1];
        bool fits = (w1 - w0 <= ICAP);
        const int* si = &sIdx[sbuf][wave * ICAP];

        // hoist all 8 offs loads (independent; issue together)
        int r0v[4], r1v[4];
#pragma unroll
        for (int t2 = 0; t2 < 4; ++t2) {
            int b = bidx0 + t2 * 4 + qd;
            r0v[t2] = offs[b];
            r1v[t2] = (b + 1 < NRSEG) ? offs[b + 1] : EE;
        }

#pragma unroll
        for (int t2 = 0; t2 < 4; ++t2) {
            int node = t2 * 4 + qd;
            int r0 = r0v[t2], r1 = r1v[t2];
            int o  = r0 - w0;
            int cnt = r1 - r0;
            float ax[8];
#pragma unroll
            for (int i = 0; i < 8; ++i) ax[i] = 0.f;

            auto upk = [&](uint4 u) {
                ax[0] += __uint_as_float(u.x << 16);
                ax[1] += __uint_as_float(u.x & 0xffff0000u);
                ax[2] += __uint_as_float(u.y << 16);
                ax[3] += __uint_as_float(u.y & 0xffff0000u);
                ax[4] += __uint_as_float(u.z << 16);
                ax[5] += __uint_as_float(u.z & 0xffff0000u);
                ax[6] += __uint_as_float(u.w << 16);
                ax[7] += __uint_as_float(u.w & 0xffff0000u);
            };

            int j = 0;
            if (fits) {
                for (; j + 8 <= cnt; j += 8) {
                    uint4 w0v = *(const uint4*)&hin[si[o+j+0] * DD + mm * 8];
                    uint4 w1v = *(const uint4*)&hin[si[o+j+1] * DD + mm * 8];
                    uint4 w2v = *(const uint4*)&hin[si[o+j+2] * DD + mm * 8];
                    uint4 w3v = *(const uint4*)&hin[si[o+j+3] * DD + mm * 8];
                    uint4 w4v = *(const uint4*)&hin[si[o+j+4] * DD + mm * 8];
                    uint4 w5v = *(const uint4*)&hin[si[o+j+5] * DD + mm * 8];
                    uint4 w6v = *(const uint4*)&hin[si[o+j+6] * DD + mm * 8];
                    uint4 w7v = *(const uint4*)&hin[si[o+j+7] * DD + mm * 8];
                    upk(w0v); upk(w1v); upk(w2v); upk(w3v);
                    upk(w4v); upk(w5v); upk(w6v); upk(w7v);
                }
                for (; j < cnt; ++j)
                    upk(*(const uint4*)&hin[si[o+j] * DD + mm * 8]);
            } else {
                for (; j + 4 <= cnt; j += 4) {
                    uint4 w0v = *(const uint4*)&hin[(int)sorted[r0+j+0] * DD + mm * 8];
                    uint4 w1v = *(const uint4*)&hin[(int)sorted[r0+j+1] * DD + mm * 8];
                    uint4 w2v = *(const uint4*)&hin[(int)sorted[r0+j+2] * DD + mm * 8];
                    uint4 w3v = *(const uint4*)&hin[(int)sorted[r0+j+3] * DD + mm * 8];
                    upk(w0v); upk(w1v); upk(w2v); upk(w3v);
                }
                for (; j < cnt; ++j)
                    upk(*(const uint4*)&hin[(int)sorted[r0+j] * DD + mm * 8]);
            }
            float s = sInv[wave * 64 + g * 16 + node];
            u32 h0 = bf16_rne(ax[0] * s), h1 = bf16_rne(ax[1] * s);
            u32 h2 = bf16_rne(ax[2] * s), h3 = bf16_rne(ax[3] * s);
            u32 h4 = bf16_rne(ax[4] * s), h5 = bf16_rne(ax[5] * s);
            u32 h6 = bf16_rne(ax[6] * s), h7 = bf16_rne(ax[7] * s);
            uint4 pk;
            pk.x = h0 | (h1 << 16); pk.y = h2 | (h3 << 16);
            pk.z = h4 | (h5 << 16); pk.w = h6 | (h7 << 16);
            writeFragQ(node, pk);
        }
    };

    // ---- prologue ----
    prefetchIdx(0, 0);                           // relation 0 indices (overlaps below)
    stage(0, 0);                                 // mat0 quarter0 DMA
    {   // prestage inv for all 4 relations (1 load/lane, wave-private)
        int g = lane >> 4, node = lane & 15;
        sInv[wave * 64 + lane] = inv[g * NN + row0 + wave * 16 + node];
    }
#pragma unroll
    for (int t2 = 0; t2 < 4; ++t2) {             // root A-frags (hin already bf16)
        int node = t2 * 4 + qd;
        uint4 u = *(const uint4*)&hin[(row0 + wave * 16 + node) * DD + mm * 8];
        writeFragQ(node, u);
    }
    __syncthreads();                             // buf0 DMA drained

    // ---- 5 matrices: mat0 = root, mat 1..4 = rel 0..3 ----
    for (int m = 0; m < 5; ++m) {
        bf16x8 AH[4];
        loadA(AH);
#pragma unroll
        for (int q = 0; q < 4; ++q) {
            int step = m * 4 + q;
            if (step + 1 < 20) stage(step + 1, (step + 1) & 1);
            mfma_quarter(step & 1, AH[q]);
            __syncthreads();                     // next buf drained; this buf free
        }
        if (m < 4) {
            if (m + 1 < 4) prefetchIdx(m + 1, (m + 1) & 1);  // hide idx latency
            gather(m, m & 1);                    // refill fH (wave-private; AH dead)
        }
    }

    // ---- epilogue ----
    float bvv[8];
#pragma unroll
    for (int nt = 0; nt < 8; ++nt) bvv[nt] = bias[nt * 16 + mm];

    if constexpr (LAST) {
        int gidx = row0 >> 7;                    // 64-node blocks never straddle graphs
#pragma unroll
        for (int nt = 0; nt < 8; ++nt) {
            float v0 = acc[nt][0], v1 = acc[nt][1], v2 = acc[nt][2], v3 = acc[nt][3];
            float v = fmaxf(fmaxf(v0, v1), fmaxf(v2, v3)) + bvv[nt];
            v = fmaxf(v, 0.f);                   // relu(max) == max(relu) per column
            v = fmaxf(v, __shfl_xor(v, 16));
            v = fmaxf(v, __shfl_xor(v, 32));
            if (lane < 16)
                atomicMax((u32*)&outF[gidx * DD + nt * 16 + mm], __float_as_uint(v));
        }
    } else {
        u16* fs = &fH[wbU];                      // bounce for coalesced bf16 rows
#pragma unroll
        for (int nt = 0; nt < 8; ++nt)
#pragma unroll
            for (int r = 0; r < 4; ++r)
                fs[(qd * 4 + r) * 128 + nt * 16 + mm] =
                    (u16)bf16_rne(fmaxf(acc[nt][r] + bvv[nt], 0.f));
        uint4* dst = (uint4*)&houtH[(row0 + wave * 16) * DD];
        const uint4* src = (const uint4*)fs;
#pragma unroll
        for (int i = 0; i < 4; ++i) dst[i * 64 + lane] = src[i * 64 + lane];
    }
}

// ---------------- launch ----------------

extern "C" void kernel_launch(void* const* d_in, const int* in_sizes, int n_in,
                              void* d_out, int out_size, void* d_ws, size_t ws_size,
                              hipStream_t stream) {
    const float* x      = (const float*)d_in[0];
    const int*   ei     = (const int*)  d_in[1];
    const int*   ea     = (const int*)  d_in[2];
    const float* W_emb  = (const float*)d_in[3];
    const float* b_emb  = (const float*)d_in[4];
    const float* W_root = (const float*)d_in[5];
    const float* W_rel  = (const float*)d_in[6];
    const float* bias   = (const float*)d_in[7];
    float* out = (float*)d_out;

    char* p = (char*)d_ws;
    u16*      h0H    = (u16*)p;      p += (size_t)NN * DD * 2;      // 16.78 MB
    u16*      h1H    = (u16*)p;      p += (size_t)NN * DD * 2;      // 16.78 MB
    u32*      bc     = (u32*)p;      p += 1024;                     // bucket counts
    u32*      bcur   = (u32*)p;      p += 1024;                     // binA cursors
    u32*      bbase  = (u32*)p;      p += 1024;                     // pristine bases
    float*    inv    = (float*)p;    p += (size_t)NRSEG * 4;        // 1 MB
    int*      offs   = (int*)p;      p += (size_t)NRSEG * 4;        // 1 MB
    u32*      binned = (u32*)p;      p += (size_t)EE * 4;           // 6.29 MB
    u16*      sorted = (u16*)p;      p += (size_t)EE * 2;           // 3.15 MB
    u16*      wtH    = (u16*)p;      p += (size_t)10 * 16384 * 2;   // 0.33 MB

    hipMemsetAsync(bc, 0, 1024, stream);

    k_front<<<1920, 256, 0, stream>>>(x, W_emb, b_emb, h0H, ei, ea, bc,
                                      W_root, W_rel, wtH, out);
    k_mini <<<1, 256, 0, stream>>>(bc, bcur, bbase);
    k_binA <<<192, 256, 0, stream>>>(ei, ea, bcur, binned);
    k_binB <<<256, 256, 0, stream>>>(binned, bbase, offs, inv, sorted);

    k_layer<0><<<NN / 64, 256, 0, stream>>>(h0H, h1H, nullptr,
                                            wtH, bias, sorted, offs, inv);
    k_layer<1><<<NN / 64, 256, 0, stream>>>(h1H, nullptr, out,
                                            wtH + 81920, bias + 128,
                                            sorted, offs, inv);
}